// Round 14
// baseline (111.340 us; speedup 1.0000x reference)
//
#include <hip/hip_runtime.h>
#include <hip/hip_bf16.h>
#include <math.h>

// B=4, S=4096, D=256, T=256, K_PATCH=8. fp32 I/O, bf16 MFMA compute, fp32 accum.
// ws = 1.07 MB; d_out tail doubles as centroid scratch (overwritten by k_mega).
// Occupancy engineering: LDS 51712 <= 160K/3 -> 3 blocks/CU; VGPR must stay <=85
// (6 waves/SIMD). Swizzle law (derived+verified r10-r12): row-coeff mod 8 in {2,4}
// plus XOR ((row&7)<<3) makes consecutive-8-lane b128 reads hit 8 distinct quads.
#define S_   4096
#define XROW 259
#define XS   272   // X tiles: coeff 34 mod 8 = 2 ✓
#define HHS  144   // hh: coeff 18 mod 8 = 2 ✓
#define PSS  32    // psb: coeff 4 mod 8 = 4 ✓
#define PES  264   // pe: linear (scalar access only)

typedef const float* fpp;
typedef __attribute__((ext_vector_type(8))) short   s8b;   // 8 bf16 = 4 VGPR
typedef __attribute__((ext_vector_type(4))) float   f32x4; // MFMA accum

__device__ __forceinline__ float us2f(unsigned short u){ return __uint_as_float(((unsigned)u)<<16); }
__device__ __forceinline__ unsigned short f2bu(float f){
  __hip_bfloat16 h = __float2bfloat16(f);
  return *reinterpret_cast<unsigned short*>(&h);
}
// sigmoid-form tanh-GELU, max abs err ~3e-4
__device__ __forceinline__ float gelu_f(float v){
  float u2 = 2.0f * v * fmaf(0.0356774081f, v*v, 0.7978845608f);
  float e  = __expf(u2);
  return v * (1.0f - __builtin_amdgcn_rcpf(e + 1.0f));
}
// XOR bank swizzles (16B-window granularity)
__device__ __forceinline__ int sxi(int row, int col){ return (row*XS  + col) ^ ((row&7)<<3); }
__device__ __forceinline__ int shh(int row, int col){ return (row*HHS + col) ^ ((row&7)<<3); }
__device__ __forceinline__ int sps(int row, int col){ return (row*PSS + col) ^ ((row&7)<<3); }

// ---------- weight prep -> MFMA fragment order; + centroid pack ----------
__global__ __launch_bounds__(256) void k_prep(
    fpp W_in, fpp Wq, fpp Wk, fpp Wv, fpp Wg1, fpp Wg2, fpp W_out, fpp Wp2, fpp Wp1,
    fpp x, unsigned short* __restrict__ FO, float4* __restrict__ cbuf)
{
  int bb = blockIdx.x, wv = threadIdx.x>>6, lane = threadIdx.x&63;
  if (bb < 192) {
    int m  = bb >> 5;
    int fi = (bb & 31)*4 + wv;            // 0..127
    int c = fi >> 3, s = fi & 7;
    int col = c*16 + (lane&15);
    int k0  = s*32 + (lane>>4)*8;
    fpp Wm = (m==0)?W_in:(m==2)?Wv:(m==3)?Wg1:(m==4)?Wg2:(m==5)?W_out:Wq;
    s8b v;
#pragma unroll
    for (int j=0;j<8;j++){
      float f = Wm[(size_t)(k0+j)*256 + col];
      if (m==1) f -= Wk[(size_t)(k0+j)*256 + col];
      v[j] = (short)f2bu(f);
    }
    *(s8b*)(FO + (size_t)m*65536 + (size_t)fi*512 + lane*8) = v;
  } else if (bb < 208) {                  // Wp2 (128,256): 64 frags
    int fi = (bb-192)*4 + wv;
    int c = fi >> 2, s = fi & 3;
    int col = c*16 + (lane&15);
    int k0  = s*32 + (lane>>4)*8;
    s8b v;
#pragma unroll
    for (int j=0;j<8;j++) v[j] = (short)f2bu(Wp2[(size_t)(k0+j)*256 + col]);
    *(s8b*)(FO + 393216 + (size_t)fi*512 + lane*8) = v;
  } else if (bb < 210) {                  // Wp1 (10,128), K-pad 32: 8 frags
    int fi = (bb-208)*4 + wv;
    int col = fi*16 + (lane&15);
    int k0  = (lane>>4)*8;
    s8b v;
#pragma unroll
    for (int j=0;j<8;j++){
      int k = k0 + j;
      v[j] = (k < 10) ? (short)f2bu(Wp1[(size_t)k*128 + col]) : (short)0;
    }
    *(s8b*)(FO + 425984 + (size_t)fi*512 + lane*8) = v;
  } else {                                // centroid pack: (x,y,z,|c|^2 / 2)
    int t = (bb-210)*256 + threadIdx.x;
    size_t xrow = (size_t)t * XROW;
    float cx = x[xrow], cy = x[xrow+1], cz = x[xrow+2];
    cbuf[t] = make_float4(cx, cy, cz, 0.5f*fmaf(cz,cz,fmaf(cy,cy,cx*cx)));
  }
}

// ---------- kNN v4 (r9-proven): 512x512, depth-4, folded score, packed keys ----------
__global__ __launch_bounds__(512,4) void k_knn(const float4* __restrict__ cbuf,
                                               unsigned short* __restrict__ idxw)
{
  __shared__ float4 cent4[S_];
  const int rowbase = blockIdx.x * 32;
  const int b = rowbase >> 12;
  const float4* cb = cbuf + (size_t)b*S_;
  for (int t = threadIdx.x; t < S_; t += 512) cent4[t] = cb[t];
  __syncthreads();
  const int r = threadIdx.x >> 4;
  const int L = threadIdx.x & 15;
  const int s = (rowbase & (S_-1)) + r;
  float4 cs = cent4[s];
  const float nsx = -cs.x, nsy = -cs.y, nsz = -cs.z;
  unsigned bk0=0xFFFFFFFFu, bk1=0xFFFFFFFFu, bk2=0xFFFFFFFFu, bk3=0xFFFFFFFFu;
  int t = L;
#pragma unroll 4
  for (int i = 0; i < 256; ++i) {
    float4 c = cent4[t];
    float m = fmaf(nsx, c.x, fmaf(nsy, c.y, fmaf(nsz, c.z, c.w)));
    unsigned ub = __float_as_uint(m);
    ub ^= ((unsigned)((int)ub >> 31)) | 0x80000000u;
    unsigned kk = (ub & 0xFFFFF000u) | (unsigned)t;
    unsigned lo;
    lo = min(kk,bk0); kk = max(kk,bk0); bk0 = lo;
    lo = min(kk,bk1); kk = max(kk,bk1); bk1 = lo;
    lo = min(kk,bk2); kk = max(kk,bk2); bk2 = lo;
    bk3 = min(kk,bk3);
    t += 16;
  }
  size_t obase = (size_t)(rowbase + r) * 8;
  int h = 0;
#pragma unroll
  for (int round = 0; round < 8; ++round) {
    unsigned mdv = (h==0)?bk0:(h==1)?bk1:(h==2)?bk2:(h==3)?bk3:0xFFFFFFFFu;
    unsigned gd = mdv;
#pragma unroll
    for (int off=1; off<16; off<<=1)
      gd = min(gd, (unsigned)__shfl_xor((int)gd, off));
    if (L == 0) idxw[obase + round] = (unsigned short)(gd & 0xFFFu);
    h += (mdv == gd) ? 1 : 0;
  }
}

// ---------- megakernel v7: 3 blocks/CU (LDS 51712), fused g+v, full swizzles ----------
__global__ __launch_bounds__(512,2) void k_mega(
    fpp x, const unsigned short* __restrict__ idxw,
    fpp bp1, fpp bp2,
    const unsigned short* __restrict__ FO,
    fpp b_in, fpp bg1, fpp bg2, fpp b_out,
    float* __restrict__ out)
{
  __shared__ __align__(16) char pool[51712];
  unsigned short* psb = (unsigned short*)pool;            // 256x32 u16 (16384 B)
  unsigned short* hh  = (unsigned short*)(pool + 16384);  // 64x144 u16 (18432 B) ends 34816
  unsigned short* X0  = (unsigned short*)pool;            // 32x272 u16 (17408 B)
  unsigned short* X1  = (unsigned short*)(pool + 17408);  // ends 34816
  unsigned short* pe  = (unsigned short*)(pool + 34816);  // 32x264 u16 (16896 B) ends 51712

  const int tid = threadIdx.x, lane = tid & 63, wv = tid >> 6;   // wv 0..7
  const int arow = lane & 15, akb = lane >> 4, rbase = akb*4;
  const int ctb = wv*2;
  const int tok0 = blockIdx.x * 32, b = tok0 >> 12;
  const unsigned short* FO2 = FO + 393216;
  const unsigned short* FO3 = FO + 425984;
  const int col0 = ctb*16 + arow, col1 = col0 + 16;

  s8b bf3 = *(const s8b*)(FO3 + wv*512 + lane*8);   // w1 fragment (4 VGPR)
  float b1v = bp1[wv*16 + arow];
  float bp2v0 = bp2[col0], bp2v1 = bp2[col1];

  // ---- stage pos_struct (256 rows = 32 tok x 8 nb), stride 32, swizzled ----
  if (tid < 256) {
    int tk = tid >> 3;
    size_t grow = (size_t)(tok0 + tk), xrow = grow * XROW;
    float cx=x[xrow], cy=x[xrow+1], cz=x[xrow+2];
    int nb = idxw[grow*8 + (tid & 7)];
    size_t nrow = ((size_t)(b*S_ + nb)) * XROW;
    float nx=x[nrow], ny=x[nrow+1], nz=x[nrow+2];
    float rx=nx-cx, ry=ny-cy, rz=nz-cz;
    float nrm = sqrtf(fmaf(rz,rz,fmaf(ry,ry,rx*rx)));
    s8b v0 = { (short)f2bu(cx),(short)f2bu(cy),(short)f2bu(cz),(short)f2bu(nx),
               (short)f2bu(ny),(short)f2bu(nz),(short)f2bu(rx),(short)f2bu(ry) };
    s8b v1 = { (short)f2bu(rz),(short)f2bu(nrm),0,0,0,0,0,0 };
    s8b vz = { 0,0,0,0,0,0,0,0 };
    *(s8b*)(psb + sps(tid, 0))  = v0;
    *(s8b*)(psb + sps(tid, 8))  = v1;
    *(s8b*)(psb + sps(tid, 16)) = vz;
    *(s8b*)(psb + sps(tid, 24)) = vz;
  }
  __syncthreads();

  // ---- posMLP: 4 chunks x (64 rows = 8 tok x 8 nb) ----
  for (int c=0;c<4;++c){
    f32x4 h4[4];
#pragma unroll
    for (int rt=0;rt<4;++rt){
      s8b af = *(const s8b*)(psb + sps(c*64 + rt*16 + arow, akb*8));
      h4[rt] = __builtin_amdgcn_mfma_f32_16x16x32_bf16(af, bf3, (f32x4){0.f,0.f,0.f,0.f}, 0,0,0);
    }
#pragma unroll
    for (int rt=0;rt<4;++rt)
#pragma unroll
      for (int rr=0;rr<4;++rr)
        hh[shh(rt*16 + rbase + rr, wv*16 + arow)] = f2bu(gelu_f(h4[rt][rr] + b1v));
    __syncthreads();
    f32x4 a2c[4][2];
#pragma unroll
    for (int rt=0;rt<4;++rt){ a2c[rt][0]=(f32x4){0.f,0.f,0.f,0.f}; a2c[rt][1]=(f32x4){0.f,0.f,0.f,0.f}; }
#pragma unroll
    for (int s=0;s<4;++s){
      s8b af0 = *(const s8b*)(hh + shh( 0 + arow, s*32 + akb*8));
      s8b af1 = *(const s8b*)(hh + shh(16 + arow, s*32 + akb*8));
      s8b af2 = *(const s8b*)(hh + shh(32 + arow, s*32 + akb*8));
      s8b af3v= *(const s8b*)(hh + shh(48 + arow, s*32 + akb*8));
#pragma unroll
      for (int i=0;i<2;++i){
        s8b bf = *(const s8b*)(FO2 + ((size_t)((ctb+i)*4 + s))*512 + lane*8);
        a2c[0][i] = __builtin_amdgcn_mfma_f32_16x16x32_bf16(af0,  bf, a2c[0][i], 0,0,0);
        a2c[1][i] = __builtin_amdgcn_mfma_f32_16x16x32_bf16(af1,  bf, a2c[1][i], 0,0,0);
        a2c[2][i] = __builtin_amdgcn_mfma_f32_16x16x32_bf16(af2,  bf, a2c[2][i], 0,0,0);
        a2c[3][i] = __builtin_amdgcn_mfma_f32_16x16x32_bf16(af3v, bf, a2c[3][i], 0,0,0);
      }
    }
#pragma unroll
    for (int rt=0;rt<4;++rt)
#pragma unroll
      for (int i=0;i<2;++i){
        float pm = fmaxf(fmaxf(a2c[rt][i][0],a2c[rt][i][1]), fmaxf(a2c[rt][i][2],a2c[rt][i][3]));
        pm = fmaxf(pm, __shfl_xor(pm, 16));       // combine neighbor halves
        if ((akb & 1) == 0)
          pe[(c*8 + rt*2 + (akb>>1))*PES + (ctb+i)*16 + arow] = f2bu(pm + (i ? bp2v1 : bp2v0));
      }
    __syncthreads();
  }

  // ---- stage pre -> X0 (b128, swizzled; psb/hh dead) ----
#pragma unroll
  for (int p=0;p<2;++p){
    int i2 = p*512 + tid;
    int row = i2 >> 5, cb2 = i2 & 31;
    const float* src = x + (size_t)(tok0 + row)*XROW + 3 + cb2*8;
    s8b v;
#pragma unroll
    for (int j=0;j<8;j++) v[j] = (short)f2bu(src[j]);
    *(s8b*)(X0 + sxi(row, cb2*8)) = v;
  }
  __syncthreads();

  f32x4 acc[2][2];
  auto gphase = [&](const unsigned short* A, const unsigned short* FOm){
#pragma unroll
    for (int rt=0;rt<2;++rt){ acc[rt][0]=(f32x4){0.f,0.f,0.f,0.f}; acc[rt][1]=(f32x4){0.f,0.f,0.f,0.f}; }
#pragma unroll
    for (int s=0;s<8;++s){
      s8b a0 = *(const s8b*)(A + sxi(arow,      s*32 + akb*8));
      s8b a1 = *(const s8b*)(A + sxi(16 + arow, s*32 + akb*8));
#pragma unroll
      for (int i=0;i<2;++i){
        s8b bf = *(const s8b*)(FOm + ((size_t)((ctb+i)*8 + s))*512 + lane*8);
        acc[0][i] = __builtin_amdgcn_mfma_f32_16x16x32_bf16(a0, bf, acc[0][i], 0,0,0);
        acc[1][i] = __builtin_amdgcn_mfma_f32_16x16x32_bf16(a1, bf, acc[1][i], 0,0,0);
      }
    }
  };

  // ---- h = pre @ W_in + b_in + pe -> X1 ----
  gphase(X0, FO);
#pragma unroll
  for (int i=0;i<2;++i){
    int col = i ? col1 : col0;
    float bi = b_in[col];
#pragma unroll
    for (int rt=0;rt<2;++rt)
#pragma unroll
      for (int rr=0;rr<4;++rr){
        int row = rt*16 + rbase + rr;
        X1[sxi(row,col)] = f2bu(acc[rt][i][rr] + bi + us2f(pe[row*PES + col]));
      }
  }
  __syncthreads();

  // ---- FUSED: g = h@(Wq-Wk) -> X0 ; v = h@Wv -> accv regs (pre dead) ----
  f32x4 accv[2][2];
  {
#pragma unroll
    for (int rt=0;rt<2;++rt){
      acc[rt][0]=(f32x4){0.f,0.f,0.f,0.f};  acc[rt][1]=(f32x4){0.f,0.f,0.f,0.f};
      accv[rt][0]=(f32x4){0.f,0.f,0.f,0.f}; accv[rt][1]=(f32x4){0.f,0.f,0.f,0.f};
    }
#pragma unroll
    for (int s=0;s<8;++s){
      s8b a0 = *(const s8b*)(X1 + sxi(arow,      s*32 + akb*8));
      s8b a1 = *(const s8b*)(X1 + sxi(16 + arow, s*32 + akb*8));
#pragma unroll
      for (int i=0;i<2;++i){
        s8b bg = *(const s8b*)(FO +  65536 + ((size_t)((ctb+i)*8 + s))*512 + lane*8);
        s8b bv = *(const s8b*)(FO + 131072 + ((size_t)((ctb+i)*8 + s))*512 + lane*8);
        acc[0][i]  = __builtin_amdgcn_mfma_f32_16x16x32_bf16(a0, bg, acc[0][i], 0,0,0);
        acc[1][i]  = __builtin_amdgcn_mfma_f32_16x16x32_bf16(a1, bg, acc[1][i], 0,0,0);
        accv[0][i] = __builtin_amdgcn_mfma_f32_16x16x32_bf16(a0, bv, accv[0][i], 0,0,0);
        accv[1][i] = __builtin_amdgcn_mfma_f32_16x16x32_bf16(a1, bv, accv[1][i], 0,0,0);
      }
    }
#pragma unroll
    for (int i=0;i<2;++i){
      int col = i ? col1 : col0;
#pragma unroll
      for (int rt=0;rt<2;++rt)
#pragma unroll
        for (int rr=0;rr<4;++rr)
          X0[sxi(rt*16 + rbase + rr, col)] = f2bu(acc[rt][i][rr]);
    }
  }
  __syncthreads();

  // ---- a1 = gelu(g @ Wg1 + bg1) -> X1 (h dead) ----
  gphase(X0, FO + 196608);
#pragma unroll
  for (int i=0;i<2;++i){
    int col = i ? col1 : col0;
    float bi = bg1[col];
#pragma unroll
    for (int rt=0;rt<2;++rt)
#pragma unroll
      for (int rr=0;rr<4;++rr)
        X1[sxi(rt*16 + rbase + rr, col)] = f2bu(gelu_f(acc[rt][i][rr] + bi));
  }
  __syncthreads();

  // ---- a2 = (a1 @ Wg2 + bg2) * 256^-0.5 -> X0 ----
  gphase(X1, FO + 262144);
#pragma unroll
  for (int i=0;i<2;++i){
    int col = i ? col1 : col0;
    float bi = bg2[col];
#pragma unroll
    for (int rt=0;rt<2;++rt)
#pragma unroll
      for (int rr=0;rr<4;++rr)
        X0[sxi(rt*16 + rbase + rr, col)] = f2bu((acc[rt][i][rr] + bi) * 0.0625f);
  }
  __syncthreads();

  // ---- softmax over 256 channels, X0 in place (32 rows x 16 lanes) ----
  {
    int row = tid >> 4, li = tid & 15;
    s8b v0 = *(const s8b*)(X0 + sxi(row, li*16));
    s8b v1 = *(const s8b*)(X0 + sxi(row, li*16 + 8));
    float f[16];
#pragma unroll
    for (int j=0;j<8;++j){ f[j] = us2f((unsigned short)v0[j]); f[8+j] = us2f((unsigned short)v1[j]); }
    float mx = f[0];
#pragma unroll
    for (int i=1;i<16;i++) mx = fmaxf(mx, f[i]);
#pragma unroll
    for (int o=1;o<16;o<<=1) mx = fmaxf(mx, __shfl_xor(mx, o));
    float ssum = 0.f;
#pragma unroll
    for (int i=0;i<16;i++){ f[i] = __expf(f[i]-mx); ssum += f[i]; }
#pragma unroll
    for (int o=1;o<16;o<<=1) ssum += __shfl_xor(ssum, o);
    float inv = __builtin_amdgcn_rcpf(ssum);
#pragma unroll
    for (int j=0;j<8;++j){ v0[j] = (short)f2bu(f[j]*inv); v1[j] = (short)f2bu(f[8+j]*inv); }
    *(s8b*)(X0 + sxi(row, li*16))     = v0;
    *(s8b*)(X0 + sxi(row, li*16 + 8)) = v1;
  }
  __syncthreads();

  // ---- r = attn * v(regs) -> X1 (a1 dead) ----
#pragma unroll
  for (int i=0;i<2;++i){
    int col = i ? col1 : col0;
#pragma unroll
    for (int rt=0;rt<2;++rt)
#pragma unroll
      for (int rr=0;rr<4;++rr){
        int row = rt*16 + rbase + rr;
        X1[sxi(row,col)] = f2bu(us2f(X0[sxi(row,col)]) * accv[rt][i][rr]);
      }
  }
  __syncthreads();

  // ---- out = r @ W_out + b_out + pre (fp32 store) ----
  gphase(X1, FO + 327680);
#pragma unroll
  for (int i=0;i<2;++i){
    int col = i ? col1 : col0;
    float bo = b_out[col];
#pragma unroll
    for (int rt=0;rt<2;++rt)
#pragma unroll
      for (int rr=0;rr<4;++rr){
        size_t row = (size_t)(tok0 + rt*16 + rbase + rr);
        out[row*256 + col] = acc[rt][i][rr] + bo + x[row*XROW + 3 + col];
      }
  }
}

extern "C" void kernel_launch(void* const* d_in, const int* in_sizes, int n_in,
                              void* d_out, int out_size, void* d_ws, size_t ws_size,
                              hipStream_t stream)
{
  fpp x    = (fpp)d_in[0];
  fpp W_in = (fpp)d_in[1];  fpp b_in = (fpp)d_in[2];
  fpp Wq   = (fpp)d_in[3];  fpp Wk   = (fpp)d_in[4];  fpp Wv = (fpp)d_in[5];
  fpp Wg1  = (fpp)d_in[6];  fpp bg1  = (fpp)d_in[7];
  fpp Wg2  = (fpp)d_in[8];  fpp bg2  = (fpp)d_in[9];
  fpp W_out= (fpp)d_in[10]; fpp b_out= (fpp)d_in[11];
  fpp Wp1  = (fpp)d_in[12]; fpp bp1  = (fpp)d_in[13];
  fpp Wp2  = (fpp)d_in[14]; fpp bp2  = (fpp)d_in[15];

  // ---- workspace: 1,122,304 bytes ----
  char* ws = (char*)d_ws;
  unsigned short* idxw = (unsigned short*)ws;            // 262144 B
  unsigned short* FO   = (unsigned short*)(ws + 262144); // 860160 B

  // centroid scratch in d_out tail (overwritten by k_mega afterwards)
  float4* cbuf = (float4*)((char*)d_out + 16515072);     // 262144 B

  k_prep<<<274, 256, 0, stream>>>(W_in,Wq,Wk,Wv,Wg1,Wg2,W_out,Wp2,Wp1, x, FO, cbuf);
  k_knn <<<512, 512, 0, stream>>>(cbuf, idxw);
  k_mega<<<512, 512, 0, stream>>>(x, idxw, bp1, bp2, FO,
                                  b_in, bg1, bg2, b_out, (float*)d_out);
}

// Round 15
// 86.828 us; speedup vs baseline: 1.2823x; 1.2823x over previous
//
#include <hip/hip_runtime.h>
#include <hip/hip_bf16.h>
#include <math.h>

// B=4, S=4096, D=256, T=256, K_PATCH=8. fp32 I/O, bf16 MFMA compute, fp32 accum.
// ws = 1.07 MB; d_out tail doubles as centroid scratch (overwritten by k_mega).
// Occupancy law (r8-r14): VGPR<=64 <=> 2+ blocks/CU resident & fast. Grid must
// supply the blocks: M=16 -> 1024 blocks = 4/CU; LDS 36.1KB*4 = 144KB <= 160KB.
#define S_   4096
#define XROW 259

typedef const float* fpp;
typedef __attribute__((ext_vector_type(8))) short   s8b;   // 8 bf16 = 4 VGPR
typedef __attribute__((ext_vector_type(4))) float   f32x4; // MFMA accum

__device__ __forceinline__ float us2f(unsigned short u){ return __uint_as_float(((unsigned)u)<<16); }
__device__ __forceinline__ unsigned short f2bu(float f){
  __hip_bfloat16 h = __float2bfloat16(f);
  return *reinterpret_cast<unsigned short*>(&h);
}
// sigmoid-form tanh-GELU, max abs err ~3e-4
__device__ __forceinline__ float gelu_f(float v){
  float u2 = 2.0f * v * fmaf(0.0356774081f, v*v, 0.7978845608f);
  float e  = __expf(u2);
  return v * (1.0f - __builtin_amdgcn_rcpf(e + 1.0f));
}

// ---------- weight prep -> MFMA fragment order; + centroid pack ----------
__global__ __launch_bounds__(256) void k_prep(
    fpp W_in, fpp Wq, fpp Wk, fpp Wv, fpp Wg1, fpp Wg2, fpp W_out, fpp Wp2, fpp Wp1,
    fpp x, unsigned short* __restrict__ FO, float4* __restrict__ cbuf)
{
  int bb = blockIdx.x, wv = threadIdx.x>>6, lane = threadIdx.x&63;
  if (bb < 192) {
    int m  = bb >> 5;
    int fi = (bb & 31)*4 + wv;            // 0..127
    int c = fi >> 3, s = fi & 7;
    int col = c*16 + (lane&15);
    int k0  = s*32 + (lane>>4)*8;
    fpp Wm = (m==0)?W_in:(m==2)?Wv:(m==3)?Wg1:(m==4)?Wg2:(m==5)?W_out:Wq;
    s8b v;
#pragma unroll
    for (int j=0;j<8;j++){
      float f = Wm[(size_t)(k0+j)*256 + col];
      if (m==1) f -= Wk[(size_t)(k0+j)*256 + col];
      v[j] = (short)f2bu(f);
    }
    *(s8b*)(FO + (size_t)m*65536 + (size_t)fi*512 + lane*8) = v;
  } else if (bb < 208) {                  // Wp2 (128,256): 64 frags
    int fi = (bb-192)*4 + wv;
    int c = fi >> 2, s = fi & 3;
    int col = c*16 + (lane&15);
    int k0  = s*32 + (lane>>4)*8;
    s8b v;
#pragma unroll
    for (int j=0;j<8;j++) v[j] = (short)f2bu(Wp2[(size_t)(k0+j)*256 + col]);
    *(s8b*)(FO + 393216 + (size_t)fi*512 + lane*8) = v;
  } else if (bb < 210) {                  // Wp1 (10,128), K-pad 32: 8 frags
    int fi = (bb-208)*4 + wv;
    int col = fi*16 + (lane&15);
    int k0  = (lane>>4)*8;
    s8b v;
#pragma unroll
    for (int j=0;j<8;j++){
      int k = k0 + j;
      v[j] = (k < 10) ? (short)f2bu(Wp1[(size_t)k*128 + col]) : (short)0;
    }
    *(s8b*)(FO + 425984 + (size_t)fi*512 + lane*8) = v;
  } else {                                // centroid pack: (x,y,z,|c|^2 / 2)
    int t = (bb-210)*256 + threadIdx.x;
    size_t xrow = (size_t)t * XROW;
    float cx = x[xrow], cy = x[xrow+1], cz = x[xrow+2];
    cbuf[t] = make_float4(cx, cy, cz, 0.5f*fmaf(cz,cz,fmaf(cy,cy,cx*cx)));
  }
}

// ---------- kNN v4 (r9/r13-proven): 512x512, depth-4, folded score, packed keys ----------
__global__ __launch_bounds__(512,4) void k_knn(const float4* __restrict__ cbuf,
                                               unsigned short* __restrict__ idxw)
{
  __shared__ float4 cent4[S_];
  const int rowbase = blockIdx.x * 32;
  const int b = rowbase >> 12;
  const float4* cb = cbuf + (size_t)b*S_;
  for (int t = threadIdx.x; t < S_; t += 512) cent4[t] = cb[t];
  __syncthreads();
  const int r = threadIdx.x >> 4;
  const int L = threadIdx.x & 15;
  const int s = (rowbase & (S_-1)) + r;
  float4 cs = cent4[s];
  const float nsx = -cs.x, nsy = -cs.y, nsz = -cs.z;
  unsigned bk0=0xFFFFFFFFu, bk1=0xFFFFFFFFu, bk2=0xFFFFFFFFu, bk3=0xFFFFFFFFu;
  int t = L;
#pragma unroll 4
  for (int i = 0; i < 256; ++i) {
    float4 c = cent4[t];
    float m = fmaf(nsx, c.x, fmaf(nsy, c.y, fmaf(nsz, c.z, c.w)));
    unsigned ub = __float_as_uint(m);
    ub ^= ((unsigned)((int)ub >> 31)) | 0x80000000u;
    unsigned kk = (ub & 0xFFFFF000u) | (unsigned)t;
    unsigned lo;
    lo = min(kk,bk0); kk = max(kk,bk0); bk0 = lo;
    lo = min(kk,bk1); kk = max(kk,bk1); bk1 = lo;
    lo = min(kk,bk2); kk = max(kk,bk2); bk2 = lo;
    bk3 = min(kk,bk3);
    t += 16;
  }
  size_t obase = (size_t)(rowbase + r) * 8;
  int h = 0;
#pragma unroll
  for (int round = 0; round < 8; ++round) {
    unsigned mdv = (h==0)?bk0:(h==1)?bk1:(h==2)?bk2:(h==3)?bk3:0xFFFFFFFFu;
    unsigned gd = mdv;
#pragma unroll
    for (int off=1; off<16; off<<=1)
      gd = min(gd, (unsigned)__shfl_xor((int)gd, off));
    if (L == 0) idxw[obase + round] = (unsigned short)(gd & 0xFFFu);
    h += (mdv == gd) ? 1 : 0;
  }
}

// ---------- megakernel v8: M=16, 512 thr, 1024 blocks (4/CU), r13 phase structure ----------
__global__ __launch_bounds__(512,4) void k_mega(
    fpp x, const unsigned short* __restrict__ idxw,
    fpp bp1, fpp bp2,
    const unsigned short* __restrict__ FO,
    fpp b_in, fpp bg1, fpp bg2, fpp b_out,
    float* __restrict__ out)
{
  __shared__ __align__(16) char pool[36096];
  unsigned short* psb = (unsigned short*)pool;            // 128x40 u16 (10240 B)
  unsigned short* hh  = (unsigned short*)(pool + 10240);  // 64x136 u16 (17408 B) ends 27648
  unsigned short* X0  = (unsigned short*)pool;            // 16x264 u16 (8448 B)
  unsigned short* X1  = (unsigned short*)(pool + 8448);
  unsigned short* X2  = (unsigned short*)(pool + 16896);  // ends 25344
  unsigned short* pe  = (unsigned short*)(pool + 27648);  // 16x264 u16 (8448 B) ends 36096

  const int tid = threadIdx.x, lane = tid & 63, wv = tid >> 6;   // wv 0..7
  const int arow = lane & 15, akb = lane >> 4, rbase = akb*4;
  const int ctb = wv*2;
  const int tok0 = blockIdx.x * 16, b = tok0 >> 12;
  const unsigned short* FO2 = FO + 393216;
  const unsigned short* FO3 = FO + 425984;
  const int col0 = ctb*16 + arow, col1 = col0 + 16;

  s8b bf3 = *(const s8b*)(FO3 + wv*512 + lane*8);   // w1 fragment (4 VGPR)
  float b1v = bp1[wv*16 + arow];
  float bp2v0 = bp2[col0], bp2v1 = bp2[col1];

  // ---- stage pos_struct (128 rows = 16 tok x 8 nb) ----
  if (tid < 128) {
    int tk = tid >> 3;
    size_t grow = (size_t)(tok0 + tk), xrow = grow * XROW;
    float cx=x[xrow], cy=x[xrow+1], cz=x[xrow+2];
    int nb = idxw[grow*8 + (tid & 7)];
    size_t nrow = ((size_t)(b*S_ + nb)) * XROW;
    float nx=x[nrow], ny=x[nrow+1], nz=x[nrow+2];
    float rx=nx-cx, ry=ny-cy, rz=nz-cz;
    float nrm = sqrtf(fmaf(rz,rz,fmaf(ry,ry,rx*rx)));
    unsigned short* p = psb + tid*40;
    s8b v0 = { (short)f2bu(cx),(short)f2bu(cy),(short)f2bu(cz),(short)f2bu(nx),
               (short)f2bu(ny),(short)f2bu(nz),(short)f2bu(rx),(short)f2bu(ry) };
    s8b v1 = { (short)f2bu(rz),(short)f2bu(nrm),0,0,0,0,0,0 };
    s8b vz = { 0,0,0,0,0,0,0,0 };
    *(s8b*)(p) = v0; *(s8b*)(p+8) = v1; *(s8b*)(p+16) = vz; *(s8b*)(p+24) = vz;
  }
  __syncthreads();

  // ---- posMLP: 2 chunks x (64 rows = 8 tok x 8 nb); L2 in 2 passes (16 acc regs) ----
  for (int c=0;c<2;++c){
    f32x4 h4[4];
#pragma unroll
    for (int rt=0;rt<4;++rt){
      s8b af = *(const s8b*)(psb + (c*64 + rt*16 + arow)*40 + akb*8);
      h4[rt] = __builtin_amdgcn_mfma_f32_16x16x32_bf16(af, bf3, (f32x4){0.f,0.f,0.f,0.f}, 0,0,0);
    }
#pragma unroll
    for (int rt=0;rt<4;++rt)
#pragma unroll
      for (int rr=0;rr<4;++rr)
        hh[(rt*16 + rbase + rr)*136 + wv*16 + arow] = f2bu(gelu_f(h4[rt][rr] + b1v));
    __syncthreads();
#pragma unroll
    for (int p=0;p<2;++p){
      f32x4 a2c[2][2];
#pragma unroll
      for (int rt=0;rt<2;++rt){ a2c[rt][0]=(f32x4){0.f,0.f,0.f,0.f}; a2c[rt][1]=(f32x4){0.f,0.f,0.f,0.f}; }
#pragma unroll
      for (int s=0;s<4;++s){
        s8b ah0 = *(const s8b*)(hh + (p*32 +      arow)*136 + s*32 + akb*8);
        s8b ah1 = *(const s8b*)(hh + (p*32 + 16 + arow)*136 + s*32 + akb*8);
#pragma unroll
        for (int i=0;i<2;++i){
          s8b bf = *(const s8b*)(FO2 + ((size_t)((ctb+i)*4 + s))*512 + lane*8);
          a2c[0][i] = __builtin_amdgcn_mfma_f32_16x16x32_bf16(ah0, bf, a2c[0][i], 0,0,0);
          a2c[1][i] = __builtin_amdgcn_mfma_f32_16x16x32_bf16(ah1, bf, a2c[1][i], 0,0,0);
        }
      }
#pragma unroll
      for (int rt=0;rt<2;++rt)
#pragma unroll
        for (int i=0;i<2;++i){
          float pm = fmaxf(fmaxf(a2c[rt][i][0],a2c[rt][i][1]), fmaxf(a2c[rt][i][2],a2c[rt][i][3]));
          pm = fmaxf(pm, __shfl_xor(pm, 16));     // combine neighbor halves
          if ((akb & 1) == 0)
            pe[(c*8 + p*4 + rt*2 + (akb>>1))*264 + (ctb+i)*16 + arow] = f2bu(pm + (i ? bp2v1 : bp2v0));
        }
    }
    __syncthreads();
  }

  // ---- stage pre -> X0 (b128; psb/hh dead) ----
  {
    int row = tid >> 5, cb2 = tid & 31;
    const float* src = x + (size_t)(tok0 + row)*XROW + 3 + cb2*8;
    s8b v;
#pragma unroll
    for (int j=0;j<8;j++) v[j] = (short)f2bu(src[j]);
    *(s8b*)(X0 + row*264 + cb2*8) = v;
  }
  __syncthreads();

  f32x4 acc[2];
  auto gphase = [&](const unsigned short* A, const unsigned short* FOm){
    acc[0]=(f32x4){0.f,0.f,0.f,0.f}; acc[1]=(f32x4){0.f,0.f,0.f,0.f};
#pragma unroll
    for (int s=0;s<8;++s){
      s8b a0 = *(const s8b*)(A + arow*264 + s*32 + akb*8);
#pragma unroll
      for (int i=0;i<2;++i){
        s8b bf = *(const s8b*)(FOm + ((size_t)((ctb+i)*8 + s))*512 + lane*8);
        acc[i] = __builtin_amdgcn_mfma_f32_16x16x32_bf16(a0, bf, acc[i], 0,0,0);
      }
    }
  };

  // ---- h = pre @ W_in + b_in + pe -> X1 ----
  gphase(X0, FO);
#pragma unroll
  for (int i=0;i<2;++i){
    int col = i ? col1 : col0;
    float bi = b_in[col];
#pragma unroll
    for (int rr=0;rr<4;++rr){
      int row = rbase + rr;
      X1[row*264 + col] = f2bu(acc[i][rr] + bi + us2f(pe[row*264 + col]));
    }
  }
  __syncthreads();

  // ---- g = h @ (Wq-Wk) -> X0 ----
  gphase(X1, FO + 65536);
#pragma unroll
  for (int i=0;i<2;++i){
    int col = i ? col1 : col0;
#pragma unroll
    for (int rr=0;rr<4;++rr)
      X0[(rbase + rr)*264 + col] = f2bu(acc[i][rr]);
  }
  __syncthreads();

  // ---- a1 = gelu(g @ Wg1 + bg1) -> X2 ----
  gphase(X0, FO + 196608);
#pragma unroll
  for (int i=0;i<2;++i){
    int col = i ? col1 : col0;
    float bi = bg1[col];
#pragma unroll
    for (int rr=0;rr<4;++rr)
      X2[(rbase + rr)*264 + col] = f2bu(gelu_f(acc[i][rr] + bi));
  }
  __syncthreads();

  // ---- a2 = (a1 @ Wg2 + bg2) * 256^-0.5 -> X0 ----
  gphase(X2, FO + 262144);
#pragma unroll
  for (int i=0;i<2;++i){
    int col = i ? col1 : col0;
    float bi = bg2[col];
#pragma unroll
    for (int rr=0;rr<4;++rr)
      X0[(rbase + rr)*264 + col] = f2bu((acc[i][rr] + bi) * 0.0625f);
  }
  __syncthreads();

  // ---- softmax over 256 channels, X0 in place (16 rows x 32 lanes) ----
  {
    int row = tid >> 5, li = tid & 31;
    unsigned short* rp = X0 + row*264 + li*8;
    s8b v0 = *(const s8b*)rp;
    float f[8];
#pragma unroll
    for (int j=0;j<8;++j) f[j] = us2f((unsigned short)v0[j]);
    float mx = f[0];
#pragma unroll
    for (int i=1;i<8;i++) mx = fmaxf(mx, f[i]);
#pragma unroll
    for (int o=1;o<32;o<<=1) mx = fmaxf(mx, __shfl_xor(mx, o));
    float ssum = 0.f;
#pragma unroll
    for (int i=0;i<8;i++){ f[i] = __expf(f[i]-mx); ssum += f[i]; }
#pragma unroll
    for (int o=1;o<32;o<<=1) ssum += __shfl_xor(ssum, o);
    float inv = __builtin_amdgcn_rcpf(ssum);
#pragma unroll
    for (int j=0;j<8;++j) v0[j] = (short)f2bu(f[j]*inv);
    *(s8b*)rp = v0;
  }
  __syncthreads();

  // ---- v = h @ Wv ; r = attn * v -> X2 ----
  gphase(X1, FO + 131072);
#pragma unroll
  for (int i=0;i<2;++i){
    int col = i ? col1 : col0;
#pragma unroll
    for (int rr=0;rr<4;++rr){
      int row = rbase + rr;
      X2[row*264 + col] = f2bu(us2f(X0[row*264 + col]) * acc[i][rr]);
    }
  }
  __syncthreads();

  // ---- out = r @ W_out + b_out + pre (fp32 store) ----
  gphase(X2, FO + 327680);
#pragma unroll
  for (int i=0;i<2;++i){
    int col = i ? col1 : col0;
    float bo = b_out[col];
#pragma unroll
    for (int rr=0;rr<4;++rr){
      size_t row = (size_t)(tok0 + rbase + rr);
      out[row*256 + col] = acc[i][rr] + bo + x[row*XROW + 3 + col];
    }
  }
}

extern "C" void kernel_launch(void* const* d_in, const int* in_sizes, int n_in,
                              void* d_out, int out_size, void* d_ws, size_t ws_size,
                              hipStream_t stream)
{
  fpp x    = (fpp)d_in[0];
  fpp W_in = (fpp)d_in[1];  fpp b_in = (fpp)d_in[2];
  fpp Wq   = (fpp)d_in[3];  fpp Wk   = (fpp)d_in[4];  fpp Wv = (fpp)d_in[5];
  fpp Wg1  = (fpp)d_in[6];  fpp bg1  = (fpp)d_in[7];
  fpp Wg2  = (fpp)d_in[8];  fpp bg2  = (fpp)d_in[9];
  fpp W_out= (fpp)d_in[10]; fpp b_out= (fpp)d_in[11];
  fpp Wp1  = (fpp)d_in[12]; fpp bp1  = (fpp)d_in[13];
  fpp Wp2  = (fpp)d_in[14]; fpp bp2  = (fpp)d_in[15];

  // ---- workspace: 1,122,304 bytes ----
  char* ws = (char*)d_ws;
  unsigned short* idxw = (unsigned short*)ws;            // 262144 B
  unsigned short* FO   = (unsigned short*)(ws + 262144); // 860160 B

  // centroid scratch in d_out tail (overwritten by k_mega afterwards)
  float4* cbuf = (float4*)((char*)d_out + 16515072);     // 262144 B

  k_prep<<<274, 256, 0, stream>>>(W_in,Wq,Wk,Wv,Wg1,Wg2,W_out,Wp2,Wp1, x, FO, cbuf);
  k_knn <<<512, 512, 0, stream>>>(cbuf, idxw);
  k_mega<<<1024,512, 0, stream>>>(x, idxw, bp1, bp2, FO,
                                  b_in, bg1, bg2, b_out, (float*)d_out);
}

// Round 16
// 73.441 us; speedup vs baseline: 1.5160x; 1.1823x over previous
//
#include <hip/hip_runtime.h>
#include <hip/hip_bf16.h>
#include <math.h>

// B=4, S=4096, D=256, T=256, K_PATCH=8. fp32 I/O, bf16 MFMA compute, fp32 accum.
// ws = 1.07 MB; d_out tail doubles as centroid scratch (overwritten by k_mega).
// k_mega: byte-identical to r13's measured-best (47.4us). k_knn: +64-bias key
// (positive floats are unsigned-order-monotone -> drop the 3-op sign map).
#define S_   4096
#define XROW 259

typedef const float* fpp;
typedef __attribute__((ext_vector_type(8))) short   s8b;   // 8 bf16 = 4 VGPR
typedef __attribute__((ext_vector_type(4))) float   f32x4; // MFMA accum

__device__ __forceinline__ float us2f(unsigned short u){ return __uint_as_float(((unsigned)u)<<16); }
__device__ __forceinline__ unsigned short f2bu(float f){
  __hip_bfloat16 h = __float2bfloat16(f);
  return *reinterpret_cast<unsigned short*>(&h);
}
// sigmoid-form tanh-GELU, max abs err ~3e-4
__device__ __forceinline__ float gelu_f(float v){
  float u2 = 2.0f * v * fmaf(0.0356774081f, v*v, 0.7978845608f);
  float e  = __expf(u2);
  return v * (1.0f - __builtin_amdgcn_rcpf(e + 1.0f));
}

// ---------- weight prep -> MFMA fragment order; + centroid pack ----------
__global__ __launch_bounds__(256) void k_prep(
    fpp W_in, fpp Wq, fpp Wk, fpp Wv, fpp Wg1, fpp Wg2, fpp W_out, fpp Wp2, fpp Wp1,
    fpp x, unsigned short* __restrict__ FO, float4* __restrict__ cbuf)
{
  int bb = blockIdx.x, wv = threadIdx.x>>6, lane = threadIdx.x&63;
  if (bb < 192) {
    int m  = bb >> 5;
    int fi = (bb & 31)*4 + wv;            // 0..127
    int c = fi >> 3, s = fi & 7;
    int col = c*16 + (lane&15);
    int k0  = s*32 + (lane>>4)*8;
    fpp Wm = (m==0)?W_in:(m==2)?Wv:(m==3)?Wg1:(m==4)?Wg2:(m==5)?W_out:Wq;
    s8b v;
#pragma unroll
    for (int j=0;j<8;j++){
      float f = Wm[(size_t)(k0+j)*256 + col];
      if (m==1) f -= Wk[(size_t)(k0+j)*256 + col];
      v[j] = (short)f2bu(f);
    }
    *(s8b*)(FO + (size_t)m*65536 + (size_t)fi*512 + lane*8) = v;
  } else if (bb < 208) {                  // Wp2 (128,256): 64 frags
    int fi = (bb-192)*4 + wv;
    int c = fi >> 2, s = fi & 3;
    int col = c*16 + (lane&15);
    int k0  = s*32 + (lane>>4)*8;
    s8b v;
#pragma unroll
    for (int j=0;j<8;j++) v[j] = (short)f2bu(Wp2[(size_t)(k0+j)*256 + col]);
    *(s8b*)(FO + 393216 + (size_t)fi*512 + lane*8) = v;
  } else if (bb < 210) {                  // Wp1 (10,128), K-pad 32: 8 frags
    int fi = (bb-208)*4 + wv;
    int col = fi*16 + (lane&15);
    int k0  = (lane>>4)*8;
    s8b v;
#pragma unroll
    for (int j=0;j<8;j++){
      int k = k0 + j;
      v[j] = (k < 10) ? (short)f2bu(Wp1[(size_t)k*128 + col]) : (short)0;
    }
    *(s8b*)(FO + 425984 + (size_t)fi*512 + lane*8) = v;
  } else {                                // centroid pack: (x,y,z,|c|^2/2 + 64)
    int t = (bb-210)*256 + threadIdx.x;
    size_t xrow = (size_t)t * XROW;
    float cx = x[xrow], cy = x[xrow+1], cz = x[xrow+2];
    cbuf[t] = make_float4(cx, cy, cz, 0.5f*fmaf(cz,cz,fmaf(cy,cy,cx*cx)) + 64.0f);
  }
}

// ---------- kNN v5: positive-biased keys (no sign map), depth-4, packed ----------
// m = |c|^2/2 - s.c + 64 > 0 (P(|s|^2>128) ~ 1e-27) -> float bits order-monotone.
__global__ __launch_bounds__(512,4) void k_knn(const float4* __restrict__ cbuf,
                                               unsigned short* __restrict__ idxw)
{
  __shared__ float4 cent4[S_];
  const int rowbase = blockIdx.x * 32;
  const int b = rowbase >> 12;
  const float4* cb = cbuf + (size_t)b*S_;
  for (int t = threadIdx.x; t < S_; t += 512) cent4[t] = cb[t];
  __syncthreads();
  const int r = threadIdx.x >> 4;
  const int L = threadIdx.x & 15;
  const int s = (rowbase & (S_-1)) + r;
  float4 cs = cent4[s];
  const float nsx = -cs.x, nsy = -cs.y, nsz = -cs.z;
  unsigned bk0=0xFFFFFFFFu, bk1=0xFFFFFFFFu, bk2=0xFFFFFFFFu, bk3=0xFFFFFFFFu;
  int t = L;
#pragma unroll 4
  for (int i = 0; i < 256; ++i) {
    float4 c = cent4[t];
    float m = fmaf(nsx, c.x, fmaf(nsy, c.y, fmaf(nsz, c.z, c.w)));
    unsigned kk = (__float_as_uint(m) & 0xFFFFF000u) | (unsigned)t;   // v_and_or_b32
    unsigned lo;
    lo = min(kk,bk0); kk = max(kk,bk0); bk0 = lo;
    lo = min(kk,bk1); kk = max(kk,bk1); bk1 = lo;
    lo = min(kk,bk2); kk = max(kk,bk2); bk2 = lo;
    bk3 = min(kk,bk3);
    t += 16;
  }
  size_t obase = (size_t)(rowbase + r) * 8;
  int h = 0;
#pragma unroll
  for (int round = 0; round < 8; ++round) {
    unsigned mdv = (h==0)?bk0:(h==1)?bk1:(h==2)?bk2:(h==3)?bk3:0xFFFFFFFFu;
    unsigned gd = mdv;
#pragma unroll
    for (int off=1; off<16; off<<=1)
      gd = min(gd, (unsigned)__shfl_xor((int)gd, off));
    if (L == 0) idxw[obase + round] = (unsigned short)(gd & 0xFFFu);
    h += (mdv == gd) ? 1 : 0;
  }
}

// ---------- megakernel (r13's measured-best, unchanged) ----------
__global__ __launch_bounds__(512,4) void k_mega(
    fpp x, const unsigned short* __restrict__ idxw,
    fpp bp1, fpp bp2,
    const unsigned short* __restrict__ FO,
    fpp b_in, fpp bg1, fpp bg2, fpp b_out,
    float* __restrict__ out)
{
  __shared__ __align__(16) char pool[50688];        // X0|X1|X2  union  psb|hh
  __shared__ __align__(16) unsigned short pe[8448]; // 32 x 264
  unsigned short* X0 = (unsigned short*)pool;       // 32 x 264 u16 each (16896 B)
  unsigned short* X1 = X0 + 8448;
  unsigned short* X2 = X1 + 8448;
  unsigned short (*psb)[40]  = (unsigned short (*)[40])pool;            // 256x40 (20480 B)
  unsigned short (*hh)[136]  = (unsigned short (*)[136])(pool + 20480); // 64x136 (17408 B)

  const int tid = threadIdx.x, lane = tid & 63, wv = tid >> 6;   // wv 0..7
  const int arow = lane & 15, akb = lane >> 4, rbase = akb*4;
  const int ctb = wv*2;
  const int tok0 = blockIdx.x * 32, b = tok0 >> 12;
  const unsigned short* FO2 = FO + 393216;
  const unsigned short* FO3 = FO + 425984;
  const int col0 = ctb*16 + arow, col1 = col0 + 16;

  s8b bf3 = *(const s8b*)(FO3 + wv*512 + lane*8);   // w1 fragment (4 VGPR only)
  float b1v = bp1[wv*16 + arow];
  float bp2v0 = bp2[col0], bp2v1 = bp2[col1];

  // ---- stage pos_struct (256 rows = 32 tok x 8 nb) ----
  if (tid < 256) {
    int tk = tid >> 3;
    size_t grow = (size_t)(tok0 + tk), xrow = grow * XROW;
    float cx=x[xrow], cy=x[xrow+1], cz=x[xrow+2];
    int nb = idxw[grow*8 + (tid & 7)];
    size_t nrow = ((size_t)(b*S_ + nb)) * XROW;
    float nx=x[nrow], ny=x[nrow+1], nz=x[nrow+2];
    float rx=nx-cx, ry=ny-cy, rz=nz-cz;
    float nrm = sqrtf(fmaf(rz,rz,fmaf(ry,ry,rx*rx)));
    unsigned short* p = psb[tid];
    s8b v0 = { (short)f2bu(cx),(short)f2bu(cy),(short)f2bu(cz),(short)f2bu(nx),
               (short)f2bu(ny),(short)f2bu(nz),(short)f2bu(rx),(short)f2bu(ry) };
    s8b v1 = { (short)f2bu(rz),(short)f2bu(nrm),0,0,0,0,0,0 };
    s8b vz = { 0,0,0,0,0,0,0,0 };
    *(s8b*)(p) = v0; *(s8b*)(p+8) = v1; *(s8b*)(p+16) = vz; *(s8b*)(p+24) = vz;
  }
  __syncthreads();

  // ---- posMLP: 4 chunks x (64 rows = 8 tok x 8 nb) ----
  for (int c=0;c<4;++c){
    f32x4 h4[4];
#pragma unroll
    for (int rt=0;rt<4;++rt){
      s8b af = *(const s8b*)(&psb[c*64 + rt*16 + arow][akb*8]);
      h4[rt] = __builtin_amdgcn_mfma_f32_16x16x32_bf16(af, bf3, (f32x4){0.f,0.f,0.f,0.f}, 0,0,0);
    }
#pragma unroll
    for (int rt=0;rt<4;++rt)
#pragma unroll
      for (int rr=0;rr<4;++rr)
        hh[rt*16 + rbase + rr][wv*16 + arow] = f2bu(gelu_f(h4[rt][rr] + b1v));
    __syncthreads();
    f32x4 a2c[4][2];
#pragma unroll
    for (int rt=0;rt<4;++rt){ a2c[rt][0]=(f32x4){0.f,0.f,0.f,0.f}; a2c[rt][1]=(f32x4){0.f,0.f,0.f,0.f}; }
#pragma unroll
    for (int s=0;s<4;++s){
      s8b af0 = *(const s8b*)(&hh[ 0 + arow][s*32 + akb*8]);
      s8b af1 = *(const s8b*)(&hh[16 + arow][s*32 + akb*8]);
      s8b af2 = *(const s8b*)(&hh[32 + arow][s*32 + akb*8]);
      s8b af3v= *(const s8b*)(&hh[48 + arow][s*32 + akb*8]);
#pragma unroll
      for (int i=0;i<2;++i){
        s8b bf = *(const s8b*)(FO2 + ((size_t)((ctb+i)*4 + s))*512 + lane*8);
        a2c[0][i] = __builtin_amdgcn_mfma_f32_16x16x32_bf16(af0,  bf, a2c[0][i], 0,0,0);
        a2c[1][i] = __builtin_amdgcn_mfma_f32_16x16x32_bf16(af1,  bf, a2c[1][i], 0,0,0);
        a2c[2][i] = __builtin_amdgcn_mfma_f32_16x16x32_bf16(af2,  bf, a2c[2][i], 0,0,0);
        a2c[3][i] = __builtin_amdgcn_mfma_f32_16x16x32_bf16(af3v, bf, a2c[3][i], 0,0,0);
      }
    }
#pragma unroll
    for (int rt=0;rt<4;++rt)
#pragma unroll
      for (int i=0;i<2;++i){
        float pm = fmaxf(fmaxf(a2c[rt][i][0],a2c[rt][i][1]), fmaxf(a2c[rt][i][2],a2c[rt][i][3]));
        pm = fmaxf(pm, __shfl_xor(pm, 16));       // combine neighbor halves
        if ((akb & 1) == 0)
          pe[(c*8 + rt*2 + (akb>>1))*264 + (ctb+i)*16 + arow] = f2bu(pm + (i ? bp2v1 : bp2v0));
      }
    __syncthreads();
  }

  // ---- stage pre -> X0 (b128 writes; psb/hh dead) ----
#pragma unroll
  for (int p=0;p<2;++p){
    int i2 = p*512 + tid;
    int row = i2 >> 5, cb2 = i2 & 31;
    const float* src = x + (size_t)(tok0 + row)*XROW + 3 + cb2*8;
    s8b v;
#pragma unroll
    for (int j=0;j<8;j++) v[j] = (short)f2bu(src[j]);
    *(s8b*)(X0 + row*264 + cb2*8) = v;
  }
  __syncthreads();

  f32x4 acc[2][2];
  auto gphase = [&](const unsigned short* A, const unsigned short* FOm){
#pragma unroll
    for (int rt=0;rt<2;++rt){ acc[rt][0]=(f32x4){0.f,0.f,0.f,0.f}; acc[rt][1]=(f32x4){0.f,0.f,0.f,0.f}; }
#pragma unroll
    for (int s=0;s<8;++s){
      s8b a0 = *(const s8b*)(A + arow*264 + s*32 + akb*8);
      s8b a1 = *(const s8b*)(A + (16+arow)*264 + s*32 + akb*8);
#pragma unroll
      for (int i=0;i<2;++i){
        s8b bf = *(const s8b*)(FOm + ((size_t)((ctb+i)*8 + s))*512 + lane*8);
        acc[0][i] = __builtin_amdgcn_mfma_f32_16x16x32_bf16(a0, bf, acc[0][i], 0,0,0);
        acc[1][i] = __builtin_amdgcn_mfma_f32_16x16x32_bf16(a1, bf, acc[1][i], 0,0,0);
      }
    }
  };

  // ---- h = pre @ W_in + b_in + pe -> X1 ----
  gphase(X0, FO);
#pragma unroll
  for (int i=0;i<2;++i){
    int col = i ? col1 : col0;
    float bi = b_in[col];
#pragma unroll
    for (int rt=0;rt<2;++rt)
#pragma unroll
      for (int rr=0;rr<4;++rr){
        int row = rt*16 + rbase + rr;
        X1[row*264 + col] = f2bu(acc[rt][i][rr] + bi + us2f(pe[row*264 + col]));
      }
  }
  __syncthreads();

  // ---- g = h @ (Wq-Wk) -> X0 ----
  gphase(X1, FO + 65536);
#pragma unroll
  for (int i=0;i<2;++i){
    int col = i ? col1 : col0;
#pragma unroll
    for (int rt=0;rt<2;++rt)
#pragma unroll
      for (int rr=0;rr<4;++rr)
        X0[(rt*16 + rbase + rr)*264 + col] = f2bu(acc[rt][i][rr]);
  }
  __syncthreads();

  // ---- a1 = gelu(g @ Wg1 + bg1) -> X2 ----
  gphase(X0, FO + 196608);
#pragma unroll
  for (int i=0;i<2;++i){
    int col = i ? col1 : col0;
    float bi = bg1[col];
#pragma unroll
    for (int rt=0;rt<2;++rt)
#pragma unroll
      for (int rr=0;rr<4;++rr)
        X2[(rt*16 + rbase + rr)*264 + col] = f2bu(gelu_f(acc[rt][i][rr] + bi));
  }
  __syncthreads();

  // ---- a2 = (a1 @ Wg2 + bg2) * 256^-0.5 -> X0 ----
  gphase(X2, FO + 262144);
#pragma unroll
  for (int i=0;i<2;++i){
    int col = i ? col1 : col0;
    float bi = bg2[col];
#pragma unroll
    for (int rt=0;rt<2;++rt)
#pragma unroll
      for (int rr=0;rr<4;++rr)
        X0[(rt*16 + rbase + rr)*264 + col] = f2bu((acc[rt][i][rr] + bi) * 0.0625f);
  }
  __syncthreads();

  // ---- softmax over 256 channels, X0 in place (32 rows, 16 lanes/row) ----
  {
    int row = tid >> 4, li = tid & 15;
    unsigned short* rp = X0 + row*264 + li*16;
    uint4 u0 = *(uint4*)rp, u1 = *(uint4*)(rp + 8);
    float f[16];
    f[0]=us2f(u0.x&0xffff); f[1]=us2f(u0.x>>16); f[2]=us2f(u0.y&0xffff); f[3]=us2f(u0.y>>16);
    f[4]=us2f(u0.z&0xffff); f[5]=us2f(u0.z>>16); f[6]=us2f(u0.w&0xffff); f[7]=us2f(u0.w>>16);
    f[8]=us2f(u1.x&0xffff); f[9]=us2f(u1.x>>16); f[10]=us2f(u1.y&0xffff); f[11]=us2f(u1.y>>16);
    f[12]=us2f(u1.z&0xffff); f[13]=us2f(u1.z>>16); f[14]=us2f(u1.w&0xffff); f[15]=us2f(u1.w>>16);
    float mx = f[0];
#pragma unroll
    for (int i=1;i<16;i++) mx = fmaxf(mx, f[i]);
#pragma unroll
    for (int o=1;o<16;o<<=1) mx = fmaxf(mx, __shfl_xor(mx, o));
    float ssum = 0.f;
#pragma unroll
    for (int i=0;i<16;i++){ f[i] = __expf(f[i]-mx); ssum += f[i]; }
#pragma unroll
    for (int o=1;o<16;o<<=1) ssum += __shfl_xor(ssum, o);
    float inv = __builtin_amdgcn_rcpf(ssum);
    uint4 w0, w1;
    w0.x=f2bu(f[0]*inv) | ((unsigned)f2bu(f[1]*inv)<<16);
    w0.y=f2bu(f[2]*inv) | ((unsigned)f2bu(f[3]*inv)<<16);
    w0.z=f2bu(f[4]*inv) | ((unsigned)f2bu(f[5]*inv)<<16);
    w0.w=f2bu(f[6]*inv) | ((unsigned)f2bu(f[7]*inv)<<16);
    w1.x=f2bu(f[8]*inv) | ((unsigned)f2bu(f[9]*inv)<<16);
    w1.y=f2bu(f[10]*inv)| ((unsigned)f2bu(f[11]*inv)<<16);
    w1.z=f2bu(f[12]*inv)| ((unsigned)f2bu(f[13]*inv)<<16);
    w1.w=f2bu(f[14]*inv)| ((unsigned)f2bu(f[15]*inv)<<16);
    *(uint4*)rp = w0; *(uint4*)(rp+8) = w1;
  }
  __syncthreads();

  // ---- v = h @ Wv ; r = attn * v -> X2 ----
  gphase(X1, FO + 131072);
#pragma unroll
  for (int i=0;i<2;++i){
    int col = i ? col1 : col0;
#pragma unroll
    for (int rt=0;rt<2;++rt)
#pragma unroll
      for (int rr=0;rr<4;++rr){
        int row = rt*16 + rbase + rr;
        X2[row*264 + col] = f2bu(us2f(X0[row*264 + col]) * acc[rt][i][rr]);
      }
  }
  __syncthreads();

  // ---- out = r @ W_out + b_out + pre (fp32 store) ----
  gphase(X2, FO + 327680);
#pragma unroll
  for (int i=0;i<2;++i){
    int col = i ? col1 : col0;
    float bo = b_out[col];
#pragma unroll
    for (int rt=0;rt<2;++rt)
#pragma unroll
      for (int rr=0;rr<4;++rr){
        size_t row = (size_t)(tok0 + rt*16 + rbase + rr);
        out[row*256 + col] = acc[rt][i][rr] + bo + x[row*XROW + 3 + col];
      }
  }
}

extern "C" void kernel_launch(void* const* d_in, const int* in_sizes, int n_in,
                              void* d_out, int out_size, void* d_ws, size_t ws_size,
                              hipStream_t stream)
{
  fpp x    = (fpp)d_in[0];
  fpp W_in = (fpp)d_in[1];  fpp b_in = (fpp)d_in[2];
  fpp Wq   = (fpp)d_in[3];  fpp Wk   = (fpp)d_in[4];  fpp Wv = (fpp)d_in[5];
  fpp Wg1  = (fpp)d_in[6];  fpp bg1  = (fpp)d_in[7];
  fpp Wg2  = (fpp)d_in[8];  fpp bg2  = (fpp)d_in[9];
  fpp W_out= (fpp)d_in[10]; fpp b_out= (fpp)d_in[11];
  fpp Wp1  = (fpp)d_in[12]; fpp bp1  = (fpp)d_in[13];
  fpp Wp2  = (fpp)d_in[14]; fpp bp2  = (fpp)d_in[15];

  // ---- workspace: 1,122,304 bytes ----
  char* ws = (char*)d_ws;
  unsigned short* idxw = (unsigned short*)ws;            // 262144 B
  unsigned short* FO   = (unsigned short*)(ws + 262144); // 860160 B

  // centroid scratch in d_out tail (overwritten by k_mega afterwards)
  float4* cbuf = (float4*)((char*)d_out + 16515072);     // 262144 B

  k_prep<<<274, 256, 0, stream>>>(W_in,Wq,Wk,Wv,Wg1,Wg2,W_out,Wp2,Wp1, x, FO, cbuf);
  k_knn <<<512, 512, 0, stream>>>(cbuf, idxw);
  k_mega<<<512, 512, 0, stream>>>(x, idxw, bp1, bp2, FO,
                                  b_in, bg1, bg2, b_out, (float*)d_out);
}

// Round 17
// 67.647 us; speedup vs baseline: 1.6459x; 1.0857x over previous
//
#include <hip/hip_runtime.h>
#include <hip/hip_bf16.h>
#include <math.h>

// B=4, S=4096, D=256, T=256, K_PATCH=8. fp32 I/O, bf16 MFMA compute, fp32 accum.
// ws = 1.07 MB; d_out tail doubles as centroid scratch (overwritten by k_mega).
// k_mega structure = r13/r16 measured-best; deltas this round: trunc-bf16 for
// intermediates, posMLP chunk=128 (4 fewer barriers). k_knn: depth-3 lists.
#define S_   4096
#define XROW 259

typedef const float* fpp;
typedef __attribute__((ext_vector_type(8))) short   s8b;   // 8 bf16 = 4 VGPR
typedef __attribute__((ext_vector_type(4))) float   f32x4; // MFMA accum

__device__ __forceinline__ float us2f(unsigned short u){ return __uint_as_float(((unsigned)u)<<16); }
__device__ __forceinline__ unsigned short f2bu(float f){   // RNE (weights/prep only)
  __hip_bfloat16 h = __float2bfloat16(f);
  return *reinterpret_cast<unsigned short*>(&h);
}
__device__ __forceinline__ unsigned short f2bt(float f){   // truncating (intermediates)
  return (unsigned short)(__float_as_uint(f) >> 16);
}
// sigmoid-form tanh-GELU, max abs err ~3e-4
__device__ __forceinline__ float gelu_f(float v){
  float u2 = 2.0f * v * fmaf(0.0356774081f, v*v, 0.7978845608f);
  float e  = __expf(u2);
  return v * (1.0f - __builtin_amdgcn_rcpf(e + 1.0f));
}

// ---------- weight prep -> MFMA fragment order; + centroid pack ----------
__global__ __launch_bounds__(256) void k_prep(
    fpp W_in, fpp Wq, fpp Wk, fpp Wv, fpp Wg1, fpp Wg2, fpp W_out, fpp Wp2, fpp Wp1,
    fpp x, unsigned short* __restrict__ FO, float4* __restrict__ cbuf)
{
  int bb = blockIdx.x, wv = threadIdx.x>>6, lane = threadIdx.x&63;
  if (bb < 192) {
    int m  = bb >> 5;
    int fi = (bb & 31)*4 + wv;            // 0..127
    int c = fi >> 3, s = fi & 7;
    int col = c*16 + (lane&15);
    int k0  = s*32 + (lane>>4)*8;
    fpp Wm = (m==0)?W_in:(m==2)?Wv:(m==3)?Wg1:(m==4)?Wg2:(m==5)?W_out:Wq;
    s8b v;
#pragma unroll
    for (int j=0;j<8;j++){
      float f = Wm[(size_t)(k0+j)*256 + col];
      if (m==1) f -= Wk[(size_t)(k0+j)*256 + col];
      v[j] = (short)f2bu(f);
    }
    *(s8b*)(FO + (size_t)m*65536 + (size_t)fi*512 + lane*8) = v;
  } else if (bb < 208) {                  // Wp2 (128,256): 64 frags
    int fi = (bb-192)*4 + wv;
    int c = fi >> 2, s = fi & 3;
    int col = c*16 + (lane&15);
    int k0  = s*32 + (lane>>4)*8;
    s8b v;
#pragma unroll
    for (int j=0;j<8;j++) v[j] = (short)f2bu(Wp2[(size_t)(k0+j)*256 + col]);
    *(s8b*)(FO + 393216 + (size_t)fi*512 + lane*8) = v;
  } else if (bb < 210) {                  // Wp1 (10,128), K-pad 32: 8 frags
    int fi = (bb-208)*4 + wv;
    int col = fi*16 + (lane&15);
    int k0  = (lane>>4)*8;
    s8b v;
#pragma unroll
    for (int j=0;j<8;j++){
      int k = k0 + j;
      v[j] = (k < 10) ? (short)f2bu(Wp1[(size_t)k*128 + col]) : (short)0;
    }
    *(s8b*)(FO + 425984 + (size_t)fi*512 + lane*8) = v;
  } else {                                // centroid pack: (x,y,z,|c|^2/2 + 64)
    int t = (bb-210)*256 + threadIdx.x;
    size_t xrow = (size_t)t * XROW;
    float cx = x[xrow], cy = x[xrow+1], cz = x[xrow+2];
    cbuf[t] = make_float4(cx, cy, cz, 0.5f*fmaf(cz,cz,fmaf(cy,cy,cx*cx)) + 64.0f);
  }
}

// ---------- kNN v6: positive-biased keys, depth-3 lists, packed ----------
__global__ __launch_bounds__(512,4) void k_knn(const float4* __restrict__ cbuf,
                                               unsigned short* __restrict__ idxw)
{
  __shared__ float4 cent4[S_];
  const int rowbase = blockIdx.x * 32;
  const int b = rowbase >> 12;
  const float4* cb = cbuf + (size_t)b*S_;
  for (int t = threadIdx.x; t < S_; t += 512) cent4[t] = cb[t];
  __syncthreads();
  const int r = threadIdx.x >> 4;
  const int L = threadIdx.x & 15;
  const int s = (rowbase & (S_-1)) + r;
  float4 cs = cent4[s];
  const float nsx = -cs.x, nsy = -cs.y, nsz = -cs.z;
  unsigned bk0=0xFFFFFFFFu, bk1=0xFFFFFFFFu, bk2=0xFFFFFFFFu;
  int t = L;
#pragma unroll 4
  for (int i = 0; i < 256; ++i) {
    float4 c = cent4[t];
    float m = fmaf(nsx, c.x, fmaf(nsy, c.y, fmaf(nsz, c.z, c.w)));
    unsigned kk = (__float_as_uint(m) & 0xFFFFF000u) | (unsigned)t;   // v_and_or_b32
    unsigned lo;
    lo = min(kk,bk0); kk = max(kk,bk0); bk0 = lo;
    lo = min(kk,bk1); kk = max(kk,bk1); bk1 = lo;
    bk2 = min(kk,bk2);
    t += 16;
  }
  size_t obase = (size_t)(rowbase + r) * 8;
  int h = 0;
#pragma unroll
  for (int round = 0; round < 8; ++round) {
    unsigned mdv = (h==0)?bk0:(h==1)?bk1:(h==2)?bk2:0xFFFFFFFFu;
    unsigned gd = mdv;
#pragma unroll
    for (int off=1; off<16; off<<=1)
      gd = min(gd, (unsigned)__shfl_xor((int)gd, off));
    if (L == 0) idxw[obase + round] = (unsigned short)(gd & 0xFFFu);
    h += (mdv == gd) ? 1 : 0;
  }
}

// ---------- megakernel (r13 structure; trunc-bf16 intermediates; posMLP chunk=128) ----------
__global__ __launch_bounds__(512,4) void k_mega(
    fpp x, const unsigned short* __restrict__ idxw,
    fpp bp1, fpp bp2,
    const unsigned short* __restrict__ FO,
    fpp b_in, fpp bg1, fpp bg2, fpp b_out,
    float* __restrict__ out)
{
  __shared__ __align__(16) char pool[55296];        // X0|X1|X2  union  psb|hh
  __shared__ __align__(16) unsigned short pe[8448]; // 32 x 264
  unsigned short* X0 = (unsigned short*)pool;       // 32 x 264 u16 each (16896 B)
  unsigned short* X1 = X0 + 8448;
  unsigned short* X2 = X1 + 8448;
  unsigned short (*psb)[40]  = (unsigned short (*)[40])pool;            // 256x40  (20480 B)
  unsigned short (*hh)[136]  = (unsigned short (*)[136])(pool + 20480); // 128x136 (34816 B)

  const int tid = threadIdx.x, lane = tid & 63, wv = tid >> 6;   // wv 0..7
  const int arow = lane & 15, akb = lane >> 4, rbase = akb*4;
  const int ctb = wv*2;
  const int tok0 = blockIdx.x * 32, b = tok0 >> 12;
  const unsigned short* FO2 = FO + 393216;
  const unsigned short* FO3 = FO + 425984;
  const int col0 = ctb*16 + arow, col1 = col0 + 16;

  s8b bf3 = *(const s8b*)(FO3 + wv*512 + lane*8);   // w1 fragment (4 VGPR only)
  float b1v = bp1[wv*16 + arow];
  float bp2v0 = bp2[col0], bp2v1 = bp2[col1];

  // ---- stage pos_struct (256 rows = 32 tok x 8 nb) ----
  if (tid < 256) {
    int tk = tid >> 3;
    size_t grow = (size_t)(tok0 + tk), xrow = grow * XROW;
    float cx=x[xrow], cy=x[xrow+1], cz=x[xrow+2];
    int nb = idxw[grow*8 + (tid & 7)];
    size_t nrow = ((size_t)(b*S_ + nb)) * XROW;
    float nx=x[nrow], ny=x[nrow+1], nz=x[nrow+2];
    float rx=nx-cx, ry=ny-cy, rz=nz-cz;
    float nrm = sqrtf(fmaf(rz,rz,fmaf(ry,ry,rx*rx)));
    unsigned short* p = psb[tid];
    s8b v0 = { (short)f2bt(cx),(short)f2bt(cy),(short)f2bt(cz),(short)f2bt(nx),
               (short)f2bt(ny),(short)f2bt(nz),(short)f2bt(rx),(short)f2bt(ry) };
    s8b v1 = { (short)f2bt(rz),(short)f2bt(nrm),0,0,0,0,0,0 };
    s8b vz = { 0,0,0,0,0,0,0,0 };
    *(s8b*)(p) = v0; *(s8b*)(p+8) = v1; *(s8b*)(p+16) = vz; *(s8b*)(p+24) = vz;
  }
  __syncthreads();

  // ---- posMLP: 2 chunks x (128 rows = 16 tok x 8 nb) ----
  for (int c=0;c<2;++c){
#pragma unroll
    for (int rt=0;rt<8;++rt){
      s8b af = *(const s8b*)(&psb[c*128 + rt*16 + arow][akb*8]);
      f32x4 h4 = __builtin_amdgcn_mfma_f32_16x16x32_bf16(af, bf3, (f32x4){0.f,0.f,0.f,0.f}, 0,0,0);
#pragma unroll
      for (int rr=0;rr<4;++rr)
        hh[rt*16 + rbase + rr][wv*16 + arow] = f2bt(gelu_f(h4[rr] + b1v));
    }
    __syncthreads();
#pragma unroll
    for (int p=0;p<2;++p){
      f32x4 a2c[4][2];
#pragma unroll
      for (int rt=0;rt<4;++rt){ a2c[rt][0]=(f32x4){0.f,0.f,0.f,0.f}; a2c[rt][1]=(f32x4){0.f,0.f,0.f,0.f}; }
#pragma unroll
      for (int s=0;s<4;++s){
        s8b af0 = *(const s8b*)(&hh[p*64 +  0 + arow][s*32 + akb*8]);
        s8b af1 = *(const s8b*)(&hh[p*64 + 16 + arow][s*32 + akb*8]);
        s8b af2 = *(const s8b*)(&hh[p*64 + 32 + arow][s*32 + akb*8]);
        s8b af3v= *(const s8b*)(&hh[p*64 + 48 + arow][s*32 + akb*8]);
#pragma unroll
        for (int i=0;i<2;++i){
          s8b bf = *(const s8b*)(FO2 + ((size_t)((ctb+i)*4 + s))*512 + lane*8);
          a2c[0][i] = __builtin_amdgcn_mfma_f32_16x16x32_bf16(af0,  bf, a2c[0][i], 0,0,0);
          a2c[1][i] = __builtin_amdgcn_mfma_f32_16x16x32_bf16(af1,  bf, a2c[1][i], 0,0,0);
          a2c[2][i] = __builtin_amdgcn_mfma_f32_16x16x32_bf16(af2,  bf, a2c[2][i], 0,0,0);
          a2c[3][i] = __builtin_amdgcn_mfma_f32_16x16x32_bf16(af3v, bf, a2c[3][i], 0,0,0);
        }
      }
#pragma unroll
      for (int rt=0;rt<4;++rt)
#pragma unroll
        for (int i=0;i<2;++i){
          float pm = fmaxf(fmaxf(a2c[rt][i][0],a2c[rt][i][1]), fmaxf(a2c[rt][i][2],a2c[rt][i][3]));
          pm = fmaxf(pm, __shfl_xor(pm, 16));     // combine neighbor halves
          if ((akb & 1) == 0)
            pe[(c*16 + p*8 + rt*2 + (akb>>1))*264 + (ctb+i)*16 + arow] = f2bt(pm + (i ? bp2v1 : bp2v0));
        }
    }
    __syncthreads();
  }

  // ---- stage pre -> X0 (b128 writes; psb/hh dead) ----
#pragma unroll
  for (int p=0;p<2;++p){
    int i2 = p*512 + tid;
    int row = i2 >> 5, cb2 = i2 & 31;
    const float* src = x + (size_t)(tok0 + row)*XROW + 3 + cb2*8;
    s8b v;
#pragma unroll
    for (int j=0;j<8;j++) v[j] = (short)f2bt(src[j]);
    *(s8b*)(X0 + row*264 + cb2*8) = v;
  }
  __syncthreads();

  f32x4 acc[2][2];
  auto gphase = [&](const unsigned short* A, const unsigned short* FOm){
#pragma unroll
    for (int rt=0;rt<2;++rt){ acc[rt][0]=(f32x4){0.f,0.f,0.f,0.f}; acc[rt][1]=(f32x4){0.f,0.f,0.f,0.f}; }
#pragma unroll
    for (int s=0;s<8;++s){
      s8b a0 = *(const s8b*)(A + arow*264 + s*32 + akb*8);
      s8b a1 = *(const s8b*)(A + (16+arow)*264 + s*32 + akb*8);
#pragma unroll
      for (int i=0;i<2;++i){
        s8b bf = *(const s8b*)(FOm + ((size_t)((ctb+i)*8 + s))*512 + lane*8);
        acc[0][i] = __builtin_amdgcn_mfma_f32_16x16x32_bf16(a0, bf, acc[0][i], 0,0,0);
        acc[1][i] = __builtin_amdgcn_mfma_f32_16x16x32_bf16(a1, bf, acc[1][i], 0,0,0);
      }
    }
  };

  // ---- h = pre @ W_in + b_in + pe -> X1 ----
  gphase(X0, FO);
#pragma unroll
  for (int i=0;i<2;++i){
    int col = i ? col1 : col0;
    float bi = b_in[col];
#pragma unroll
    for (int rt=0;rt<2;++rt)
#pragma unroll
      for (int rr=0;rr<4;++rr){
        int row = rt*16 + rbase + rr;
        X1[row*264 + col] = f2bt(acc[rt][i][rr] + bi + us2f(pe[row*264 + col]));
      }
  }
  __syncthreads();

  // ---- g = h @ (Wq-Wk) -> X0 ----
  gphase(X1, FO + 65536);
#pragma unroll
  for (int i=0;i<2;++i){
    int col = i ? col1 : col0;
#pragma unroll
    for (int rt=0;rt<2;++rt)
#pragma unroll
      for (int rr=0;rr<4;++rr)
        X0[(rt*16 + rbase + rr)*264 + col] = f2bt(acc[rt][i][rr]);
  }
  __syncthreads();

  // ---- a1 = gelu(g @ Wg1 + bg1) -> X2 ----
  gphase(X0, FO + 196608);
#pragma unroll
  for (int i=0;i<2;++i){
    int col = i ? col1 : col0;
    float bi = bg1[col];
#pragma unroll
    for (int rt=0;rt<2;++rt)
#pragma unroll
      for (int rr=0;rr<4;++rr)
        X2[(rt*16 + rbase + rr)*264 + col] = f2bt(gelu_f(acc[rt][i][rr] + bi));
  }
  __syncthreads();

  // ---- a2 = (a1 @ Wg2 + bg2) * 256^-0.5 -> X0 ----
  gphase(X2, FO + 262144);
#pragma unroll
  for (int i=0;i<2;++i){
    int col = i ? col1 : col0;
    float bi = bg2[col];
#pragma unroll
    for (int rt=0;rt<2;++rt)
#pragma unroll
      for (int rr=0;rr<4;++rr)
        X0[(rt*16 + rbase + rr)*264 + col] = f2bt((acc[rt][i][rr] + bi) * 0.0625f);
  }
  __syncthreads();

  // ---- softmax over 256 channels, X0 in place (32 rows, 16 lanes/row) ----
  {
    int row = tid >> 4, li = tid & 15;
    unsigned short* rp = X0 + row*264 + li*16;
    uint4 u0 = *(uint4*)rp, u1 = *(uint4*)(rp + 8);
    float f[16];
    f[0]=us2f(u0.x&0xffff); f[1]=us2f(u0.x>>16); f[2]=us2f(u0.y&0xffff); f[3]=us2f(u0.y>>16);
    f[4]=us2f(u0.z&0xffff); f[5]=us2f(u0.z>>16); f[6]=us2f(u0.w&0xffff); f[7]=us2f(u0.w>>16);
    f[8]=us2f(u1.x&0xffff); f[9]=us2f(u1.x>>16); f[10]=us2f(u1.y&0xffff); f[11]=us2f(u1.y>>16);
    f[12]=us2f(u1.z&0xffff); f[13]=us2f(u1.z>>16); f[14]=us2f(u1.w&0xffff); f[15]=us2f(u1.w>>16);
    float mx = f[0];
#pragma unroll
    for (int i=1;i<16;i++) mx = fmaxf(mx, f[i]);
#pragma unroll
    for (int o=1;o<16;o<<=1) mx = fmaxf(mx, __shfl_xor(mx, o));
    float ssum = 0.f;
#pragma unroll
    for (int i=0;i<16;i++){ f[i] = __expf(f[i]-mx); ssum += f[i]; }
#pragma unroll
    for (int o=1;o<16;o<<=1) ssum += __shfl_xor(ssum, o);
    float inv = __builtin_amdgcn_rcpf(ssum);
    uint4 w0, w1;
    w0.x=f2bt(f[0]*inv) | ((unsigned)f2bt(f[1]*inv)<<16);
    w0.y=f2bt(f[2]*inv) | ((unsigned)f2bt(f[3]*inv)<<16);
    w0.z=f2bt(f[4]*inv) | ((unsigned)f2bt(f[5]*inv)<<16);
    w0.w=f2bt(f[6]*inv) | ((unsigned)f2bt(f[7]*inv)<<16);
    w1.x=f2bt(f[8]*inv) | ((unsigned)f2bt(f[9]*inv)<<16);
    w1.y=f2bt(f[10]*inv)| ((unsigned)f2bt(f[11]*inv)<<16);
    w1.z=f2bt(f[12]*inv)| ((unsigned)f2bt(f[13]*inv)<<16);
    w1.w=f2bt(f[14]*inv)| ((unsigned)f2bt(f[15]*inv)<<16);
    *(uint4*)rp = w0; *(uint4*)(rp+8) = w1;
  }
  __syncthreads();

  // ---- v = h @ Wv ; r = attn * v -> X2 ----
  gphase(X1, FO + 131072);
#pragma unroll
  for (int i=0;i<2;++i){
    int col = i ? col1 : col0;
#pragma unroll
    for (int rt=0;rt<2;++rt)
#pragma unroll
      for (int rr=0;rr<4;++rr){
        int row = rt*16 + rbase + rr;
        X2[row*264 + col] = f2bt(us2f(X0[row*264 + col]) * acc[rt][i][rr]);
      }
  }
  __syncthreads();

  // ---- out = r @ W_out + b_out + pre (fp32 store) ----
  gphase(X2, FO + 327680);
#pragma unroll
  for (int i=0;i<2;++i){
    int col = i ? col1 : col0;
    float bo = b_out[col];
#pragma unroll
    for (int rt=0;rt<2;++rt)
#pragma unroll
      for (int rr=0;rr<4;++rr){
        size_t row = (size_t)(tok0 + rt*16 + rbase + rr);
        out[row*256 + col] = acc[rt][i][rr] + bo + x[row*XROW + 3 + col];
      }
  }
}

extern "C" void kernel_launch(void* const* d_in, const int* in_sizes, int n_in,
                              void* d_out, int out_size, void* d_ws, size_t ws_size,
                              hipStream_t stream)
{
  fpp x    = (fpp)d_in[0];
  fpp W_in = (fpp)d_in[1];  fpp b_in = (fpp)d_in[2];
  fpp Wq   = (fpp)d_in[3];  fpp Wk   = (fpp)d_in[4];  fpp Wv = (fpp)d_in[5];
  fpp Wg1  = (fpp)d_in[6];  fpp bg1  = (fpp)d_in[7];
  fpp Wg2  = (fpp)d_in[8];  fpp bg2  = (fpp)d_in[9];
  fpp W_out= (fpp)d_in[10]; fpp b_out= (fpp)d_in[11];
  fpp Wp1  = (fpp)d_in[12]; fpp bp1  = (fpp)d_in[13];
  fpp Wp2  = (fpp)d_in[14]; fpp bp2  = (fpp)d_in[15];

  // ---- workspace: 1,122,304 bytes ----
  char* ws = (char*)d_ws;
  unsigned short* idxw = (unsigned short*)ws;            // 262144 B
  unsigned short* FO   = (unsigned short*)(ws + 262144); // 860160 B

  // centroid scratch in d_out tail (overwritten by k_mega afterwards)
  float4* cbuf = (float4*)((char*)d_out + 16515072);     // 262144 B

  k_prep<<<274, 256, 0, stream>>>(W_in,Wq,Wk,Wv,Wg1,Wg2,W_out,Wp2,Wp1, x, FO, cbuf);
  k_knn <<<512, 512, 0, stream>>>(cbuf, idxw);
  k_mega<<<512, 512, 0, stream>>>(x, idxw, bp1, bp2, FO,
                                  b_in, bg1, bg2, b_out, (float*)d_out);
}

// Round 18
// 64.331 us; speedup vs baseline: 1.7307x; 1.0515x over previous
//
#include <hip/hip_runtime.h>
#include <hip/hip_bf16.h>
#include <math.h>

// B=4, S=4096, D=256, T=256, K_PATCH=8. fp32 I/O, bf16 MFMA compute, fp32 accum.
// ws = 1.07 MB: cbuf(256K) + FO(860K). kNN fused into k_mega (nbi via LDS);
// cbuf moved to ws to avoid d_out read/write race in the fused kernel.
#define S_   4096
#define XROW 259

typedef const float* fpp;
typedef __attribute__((ext_vector_type(8))) short   s8b;   // 8 bf16 = 4 VGPR
typedef __attribute__((ext_vector_type(4))) float   f32x4; // MFMA accum

__device__ __forceinline__ float us2f(unsigned short u){ return __uint_as_float(((unsigned)u)<<16); }
__device__ __forceinline__ unsigned short f2bu(float f){   // RNE (weights/prep only)
  __hip_bfloat16 h = __float2bfloat16(f);
  return *reinterpret_cast<unsigned short*>(&h);
}
__device__ __forceinline__ unsigned short f2bt(float f){   // truncating (intermediates)
  return (unsigned short)(__float_as_uint(f) >> 16);
}
// sigmoid-form tanh-GELU, max abs err ~3e-4
__device__ __forceinline__ float gelu_f(float v){
  float u2 = 2.0f * v * fmaf(0.0356774081f, v*v, 0.7978845608f);
  float e  = __expf(u2);
  return v * (1.0f - __builtin_amdgcn_rcpf(e + 1.0f));
}

// ---------- weight prep -> MFMA fragment order; + centroid pack ----------
__global__ __launch_bounds__(256) void k_prep(
    fpp W_in, fpp Wq, fpp Wk, fpp Wv, fpp Wg1, fpp Wg2, fpp W_out, fpp Wp2, fpp Wp1,
    fpp x, unsigned short* __restrict__ FO, float4* __restrict__ cbuf)
{
  int bb = blockIdx.x, wv = threadIdx.x>>6, lane = threadIdx.x&63;
  if (bb < 192) {
    int m  = bb >> 5;
    int fi = (bb & 31)*4 + wv;            // 0..127
    int c = fi >> 3, s = fi & 7;
    int col = c*16 + (lane&15);
    int k0  = s*32 + (lane>>4)*8;
    fpp Wm = (m==0)?W_in:(m==2)?Wv:(m==3)?Wg1:(m==4)?Wg2:(m==5)?W_out:Wq;
    s8b v;
#pragma unroll
    for (int j=0;j<8;j++){
      float f = Wm[(size_t)(k0+j)*256 + col];
      if (m==1) f -= Wk[(size_t)(k0+j)*256 + col];
      v[j] = (short)f2bu(f);
    }
    *(s8b*)(FO + (size_t)m*65536 + (size_t)fi*512 + lane*8) = v;
  } else if (bb < 208) {                  // Wp2 (128,256): 64 frags
    int fi = (bb-192)*4 + wv;
    int c = fi >> 2, s = fi & 3;
    int col = c*16 + (lane&15);
    int k0  = s*32 + (lane>>4)*8;
    s8b v;
#pragma unroll
    for (int j=0;j<8;j++) v[j] = (short)f2bu(Wp2[(size_t)(k0+j)*256 + col]);
    *(s8b*)(FO + 393216 + (size_t)fi*512 + lane*8) = v;
  } else if (bb < 210) {                  // Wp1 (10,128), K-pad 32: 8 frags
    int fi = (bb-208)*4 + wv;
    int col = fi*16 + (lane&15);
    int k0  = (lane>>4)*8;
    s8b v;
#pragma unroll
    for (int j=0;j<8;j++){
      int k = k0 + j;
      v[j] = (k < 10) ? (short)f2bu(Wp1[(size_t)k*128 + col]) : (short)0;
    }
    *(s8b*)(FO + 425984 + (size_t)fi*512 + lane*8) = v;
  } else {                                // centroid pack: (x,y,z,|c|^2/2 + 64)
    int t = (bb-210)*256 + threadIdx.x;
    size_t xrow = (size_t)t * XROW;
    float cx = x[xrow], cy = x[xrow+1], cz = x[xrow+2];
    cbuf[t] = make_float4(cx, cy, cz, 0.5f*fmaf(cz,cz,fmaf(cy,cy,cx*cx)) + 64.0f);
  }
}

// ---------- fused megakernel: kNN (r17's k_knn verbatim, LDS output) + r17 mega ----------
__global__ __launch_bounds__(512,4) void k_mega(
    fpp x, const float4* __restrict__ cbuf,
    fpp bp1, fpp bp2,
    const unsigned short* __restrict__ FO,
    fpp b_in, fpp bg1, fpp bg2, fpp b_out,
    float* __restrict__ out)
{
  __shared__ __align__(16) char pool[72192];
  __shared__ __align__(8) unsigned short nbi[256];   // 32 tok x 8 nb (knn -> psb)
  float4* cent4 = (float4*)pool;                     // 4096x16 = 65536 B (knn phase)
  unsigned short* X0 = (unsigned short*)pool;        // 32x264 u16 each (16896 B)
  unsigned short* X1 = X0 + 8448;
  unsigned short* X2 = X1 + 8448;
  unsigned short (*psb)[40]  = (unsigned short (*)[40])pool;            // 256x40  (20480 B)
  unsigned short (*hh)[136]  = (unsigned short (*)[136])(pool + 20480); // 128x136 (34816 B) ends 55296
  unsigned short* pe = (unsigned short*)(pool + 55296);                 // 32x264 (16896 B) ends 72192

  const int tid = threadIdx.x, lane = tid & 63, wv = tid >> 6;   // wv 0..7
  const int arow = lane & 15, akb = lane >> 4, rbase = akb*4;
  const int ctb = wv*2;
  const int tok0 = blockIdx.x * 32, b = tok0 >> 12;
  const unsigned short* FO2 = FO + 393216;
  const unsigned short* FO3 = FO + 425984;
  const int col0 = ctb*16 + arow, col1 = col0 + 16;

  // ---- phase 0: stage centroids (coalesced) ----
  {
    const float4* cb = cbuf + (size_t)b*S_;
    for (int t = tid; t < S_; t += 512) cent4[t] = cb[t];
  }
  __syncthreads();

  // ---- phase 1: kNN (depth-3, positive-biased keys) -> nbi ----
  {
    const int r = tid >> 4;
    const int L = tid & 15;
    const int s = (tok0 & (S_-1)) + r;
    float4 cs = cent4[s];
    const float nsx = -cs.x, nsy = -cs.y, nsz = -cs.z;
    unsigned bk0=0xFFFFFFFFu, bk1=0xFFFFFFFFu, bk2=0xFFFFFFFFu;
    int t = L;
#pragma unroll 4
    for (int i = 0; i < 256; ++i) {
      float4 c = cent4[t];
      float m = fmaf(nsx, c.x, fmaf(nsy, c.y, fmaf(nsz, c.z, c.w)));
      unsigned kk = (__float_as_uint(m) & 0xFFFFF000u) | (unsigned)t;
      unsigned lo;
      lo = min(kk,bk0); kk = max(kk,bk0); bk0 = lo;
      lo = min(kk,bk1); kk = max(kk,bk1); bk1 = lo;
      bk2 = min(kk,bk2);
      t += 16;
    }
    int h = 0;
#pragma unroll
    for (int round = 0; round < 8; ++round) {
      unsigned mdv = (h==0)?bk0:(h==1)?bk1:(h==2)?bk2:0xFFFFFFFFu;
      unsigned gd = mdv;
#pragma unroll
      for (int off=1; off<16; off<<=1)
        gd = min(gd, (unsigned)__shfl_xor((int)gd, off));
      if (L == 0) nbi[r*8 + round] = (unsigned short)(gd & 0xFFFu);
      h += (mdv == gd) ? 1 : 0;
    }
  }
  __syncthreads();                                   // cent4 dead after this

  s8b bf3 = *(const s8b*)(FO3 + wv*512 + lane*8);    // w1 fragment (4 VGPR)
  float b1v = bp1[wv*16 + arow];
  float bp2v0 = bp2[col0], bp2v1 = bp2[col1];

  // ---- stage pos_struct (256 rows = 32 tok x 8 nb) ----
  if (tid < 256) {
    int tk = tid >> 3;
    size_t grow = (size_t)(tok0 + tk), xrow = grow * XROW;
    float cx=x[xrow], cy=x[xrow+1], cz=x[xrow+2];
    int nb = nbi[tid];
    size_t nrow = ((size_t)(b*S_ + nb)) * XROW;
    float nx=x[nrow], ny=x[nrow+1], nz=x[nrow+2];
    float rx=nx-cx, ry=ny-cy, rz=nz-cz;
    float nrm = sqrtf(fmaf(rz,rz,fmaf(ry,ry,rx*rx)));
    unsigned short* p = psb[tid];
    s8b v0 = { (short)f2bt(cx),(short)f2bt(cy),(short)f2bt(cz),(short)f2bt(nx),
               (short)f2bt(ny),(short)f2bt(nz),(short)f2bt(rx),(short)f2bt(ry) };
    s8b v1 = { (short)f2bt(rz),(short)f2bt(nrm),0,0,0,0,0,0 };
    s8b vz = { 0,0,0,0,0,0,0,0 };
    *(s8b*)(p) = v0; *(s8b*)(p+8) = v1; *(s8b*)(p+16) = vz; *(s8b*)(p+24) = vz;
  }
  __syncthreads();

  // ---- posMLP: 2 chunks x (128 rows = 16 tok x 8 nb) ----
  for (int c=0;c<2;++c){
#pragma unroll
    for (int rt=0;rt<8;++rt){
      s8b af = *(const s8b*)(&psb[c*128 + rt*16 + arow][akb*8]);
      f32x4 h4 = __builtin_amdgcn_mfma_f32_16x16x32_bf16(af, bf3, (f32x4){0.f,0.f,0.f,0.f}, 0,0,0);
#pragma unroll
      for (int rr=0;rr<4;++rr)
        hh[rt*16 + rbase + rr][wv*16 + arow] = f2bt(gelu_f(h4[rr] + b1v));
    }
    __syncthreads();
#pragma unroll
    for (int p=0;p<2;++p){
      f32x4 a2c[4][2];
#pragma unroll
      for (int rt=0;rt<4;++rt){ a2c[rt][0]=(f32x4){0.f,0.f,0.f,0.f}; a2c[rt][1]=(f32x4){0.f,0.f,0.f,0.f}; }
#pragma unroll
      for (int s=0;s<4;++s){
        s8b af0 = *(const s8b*)(&hh[p*64 +  0 + arow][s*32 + akb*8]);
        s8b af1 = *(const s8b*)(&hh[p*64 + 16 + arow][s*32 + akb*8]);
        s8b af2 = *(const s8b*)(&hh[p*64 + 32 + arow][s*32 + akb*8]);
        s8b af3v= *(const s8b*)(&hh[p*64 + 48 + arow][s*32 + akb*8]);
#pragma unroll
        for (int i=0;i<2;++i){
          s8b bf = *(const s8b*)(FO2 + ((size_t)((ctb+i)*4 + s))*512 + lane*8);
          a2c[0][i] = __builtin_amdgcn_mfma_f32_16x16x32_bf16(af0,  bf, a2c[0][i], 0,0,0);
          a2c[1][i] = __builtin_amdgcn_mfma_f32_16x16x32_bf16(af1,  bf, a2c[1][i], 0,0,0);
          a2c[2][i] = __builtin_amdgcn_mfma_f32_16x16x32_bf16(af2,  bf, a2c[2][i], 0,0,0);
          a2c[3][i] = __builtin_amdgcn_mfma_f32_16x16x32_bf16(af3v, bf, a2c[3][i], 0,0,0);
        }
      }
#pragma unroll
      for (int rt=0;rt<4;++rt)
#pragma unroll
        for (int i=0;i<2;++i){
          float pm = fmaxf(fmaxf(a2c[rt][i][0],a2c[rt][i][1]), fmaxf(a2c[rt][i][2],a2c[rt][i][3]));
          pm = fmaxf(pm, __shfl_xor(pm, 16));     // combine neighbor halves
          if ((akb & 1) == 0)
            pe[(c*16 + p*8 + rt*2 + (akb>>1))*264 + (ctb+i)*16 + arow] = f2bt(pm + (i ? bp2v1 : bp2v0));
        }
    }
    __syncthreads();
  }

  // ---- stage pre -> X0 (b128 writes; psb/hh dead; pe persists) ----
#pragma unroll
  for (int p=0;p<2;++p){
    int i2 = p*512 + tid;
    int row = i2 >> 5, cb2 = i2 & 31;
    const float* src = x + (size_t)(tok0 + row)*XROW + 3 + cb2*8;
    s8b v;
#pragma unroll
    for (int j=0;j<8;j++) v[j] = (short)f2bt(src[j]);
    *(s8b*)(X0 + row*264 + cb2*8) = v;
  }
  __syncthreads();

  f32x4 acc[2][2];
  auto gphase = [&](const unsigned short* A, const unsigned short* FOm){
#pragma unroll
    for (int rt=0;rt<2;++rt){ acc[rt][0]=(f32x4){0.f,0.f,0.f,0.f}; acc[rt][1]=(f32x4){0.f,0.f,0.f,0.f}; }
#pragma unroll
    for (int s=0;s<8;++s){
      s8b a0 = *(const s8b*)(A + arow*264 + s*32 + akb*8);
      s8b a1 = *(const s8b*)(A + (16+arow)*264 + s*32 + akb*8);
#pragma unroll
      for (int i=0;i<2;++i){
        s8b bf = *(const s8b*)(FOm + ((size_t)((ctb+i)*8 + s))*512 + lane*8);
        acc[0][i] = __builtin_amdgcn_mfma_f32_16x16x32_bf16(a0, bf, acc[0][i], 0,0,0);
        acc[1][i] = __builtin_amdgcn_mfma_f32_16x16x32_bf16(a1, bf, acc[1][i], 0,0,0);
      }
    }
  };

  // ---- h = pre @ W_in + b_in + pe -> X1 ----
  gphase(X0, FO);
#pragma unroll
  for (int i=0;i<2;++i){
    int col = i ? col1 : col0;
    float bi = b_in[col];
#pragma unroll
    for (int rt=0;rt<2;++rt)
#pragma unroll
      for (int rr=0;rr<4;++rr){
        int row = rt*16 + rbase + rr;
        X1[row*264 + col] = f2bt(acc[rt][i][rr] + bi + us2f(pe[row*264 + col]));
      }
  }
  __syncthreads();

  // ---- g = h @ (Wq-Wk) -> X0 ----
  gphase(X1, FO + 65536);
#pragma unroll
  for (int i=0;i<2;++i){
    int col = i ? col1 : col0;
#pragma unroll
    for (int rt=0;rt<2;++rt)
#pragma unroll
      for (int rr=0;rr<4;++rr)
        X0[(rt*16 + rbase + rr)*264 + col] = f2bt(acc[rt][i][rr]);
  }
  __syncthreads();

  // ---- a1 = gelu(g @ Wg1 + bg1) -> X2 ----
  gphase(X0, FO + 196608);
#pragma unroll
  for (int i=0;i<2;++i){
    int col = i ? col1 : col0;
    float bi = bg1[col];
#pragma unroll
    for (int rt=0;rt<2;++rt)
#pragma unroll
      for (int rr=0;rr<4;++rr)
        X2[(rt*16 + rbase + rr)*264 + col] = f2bt(gelu_f(acc[rt][i][rr] + bi));
  }
  __syncthreads();

  // ---- a2 = (a1 @ Wg2 + bg2) * 256^-0.5 -> X0 ----
  gphase(X2, FO + 262144);
#pragma unroll
  for (int i=0;i<2;++i){
    int col = i ? col1 : col0;
    float bi = bg2[col];
#pragma unroll
    for (int rt=0;rt<2;++rt)
#pragma unroll
      for (int rr=0;rr<4;++rr)
        X0[(rt*16 + rbase + rr)*264 + col] = f2bt((acc[rt][i][rr] + bi) * 0.0625f);
  }
  __syncthreads();

  // ---- softmax over 256 channels, X0 in place (32 rows, 16 lanes/row) ----
  {
    int row = tid >> 4, li = tid & 15;
    unsigned short* rp = X0 + row*264 + li*16;
    uint4 u0 = *(uint4*)rp, u1 = *(uint4*)(rp + 8);
    float f[16];
    f[0]=us2f(u0.x&0xffff); f[1]=us2f(u0.x>>16); f[2]=us2f(u0.y&0xffff); f[3]=us2f(u0.y>>16);
    f[4]=us2f(u0.z&0xffff); f[5]=us2f(u0.z>>16); f[6]=us2f(u0.w&0xffff); f[7]=us2f(u0.w>>16);
    f[8]=us2f(u1.x&0xffff); f[9]=us2f(u1.x>>16); f[10]=us2f(u1.y&0xffff); f[11]=us2f(u1.y>>16);
    f[12]=us2f(u1.z&0xffff); f[13]=us2f(u1.z>>16); f[14]=us2f(u1.w&0xffff); f[15]=us2f(u1.w>>16);
    float mx = f[0];
#pragma unroll
    for (int i=1;i<16;i++) mx = fmaxf(mx, f[i]);
#pragma unroll
    for (int o=1;o<16;o<<=1) mx = fmaxf(mx, __shfl_xor(mx, o));
    float ssum = 0.f;
#pragma unroll
    for (int i=0;i<16;i++){ f[i] = __expf(f[i]-mx); ssum += f[i]; }
#pragma unroll
    for (int o=1;o<16;o<<=1) ssum += __shfl_xor(ssum, o);
    float inv = __builtin_amdgcn_rcpf(ssum);
    uint4 w0, w1;
    w0.x=f2bt(f[0]*inv) | ((unsigned)f2bt(f[1]*inv)<<16);
    w0.y=f2bt(f[2]*inv) | ((unsigned)f2bt(f[3]*inv)<<16);
    w0.z=f2bt(f[4]*inv) | ((unsigned)f2bt(f[5]*inv)<<16);
    w0.w=f2bt(f[6]*inv) | ((unsigned)f2bt(f[7]*inv)<<16);
    w1.x=f2bt(f[8]*inv) | ((unsigned)f2bt(f[9]*inv)<<16);
    w1.y=f2bt(f[10]*inv)| ((unsigned)f2bt(f[11]*inv)<<16);
    w1.z=f2bt(f[12]*inv)| ((unsigned)f2bt(f[13]*inv)<<16);
    w1.w=f2bt(f[14]*inv)| ((unsigned)f2bt(f[15]*inv)<<16);
    *(uint4*)rp = w0; *(uint4*)(rp+8) = w1;
  }
  __syncthreads();

  // ---- v = h @ Wv ; r = attn * v -> X2 ----
  gphase(X1, FO + 131072);
#pragma unroll
  for (int i=0;i<2;++i){
    int col = i ? col1 : col0;
#pragma unroll
    for (int rt=0;rt<2;++rt)
#pragma unroll
      for (int rr=0;rr<4;++rr){
        int row = rt*16 + rbase + rr;
        X2[row*264 + col] = f2bt(us2f(X0[row*264 + col]) * acc[rt][i][rr]);
      }
  }
  __syncthreads();

  // ---- out = r @ W_out + b_out + pre (fp32 store) ----
  gphase(X2, FO + 327680);
#pragma unroll
  for (int i=0;i<2;++i){
    int col = i ? col1 : col0;
    float bo = b_out[col];
#pragma unroll
    for (int rt=0;rt<2;++rt)
#pragma unroll
      for (int rr=0;rr<4;++rr){
        size_t row = (size_t)(tok0 + rt*16 + rbase + rr);
        out[row*256 + col] = acc[rt][i][rr] + bo + x[row*XROW + 3 + col];
      }
  }
}

extern "C" void kernel_launch(void* const* d_in, const int* in_sizes, int n_in,
                              void* d_out, int out_size, void* d_ws, size_t ws_size,
                              hipStream_t stream)
{
  fpp x    = (fpp)d_in[0];
  fpp W_in = (fpp)d_in[1];  fpp b_in = (fpp)d_in[2];
  fpp Wq   = (fpp)d_in[3];  fpp Wk   = (fpp)d_in[4];  fpp Wv = (fpp)d_in[5];
  fpp Wg1  = (fpp)d_in[6];  fpp bg1  = (fpp)d_in[7];
  fpp Wg2  = (fpp)d_in[8];  fpp bg2  = (fpp)d_in[9];
  fpp W_out= (fpp)d_in[10]; fpp b_out= (fpp)d_in[11];
  fpp Wp1  = (fpp)d_in[12]; fpp bp1  = (fpp)d_in[13];
  fpp Wp2  = (fpp)d_in[14]; fpp bp2  = (fpp)d_in[15];

  // ---- workspace: 1,122,304 bytes ----
  char* ws = (char*)d_ws;
  float4* cbuf        = (float4*)ws;                     // 16384 x 16 = 262144 B
  unsigned short* FO  = (unsigned short*)(ws + 262144);  // 860160 B

  k_prep<<<274, 256, 0, stream>>>(W_in,Wq,Wk,Wv,Wg1,Wg2,W_out,Wp2,Wp1, x, FO, cbuf);
  k_mega<<<512, 512, 0, stream>>>(x, cbuf, bp1, bp2, FO,
                                  b_in, bg1, bg2, b_out, (float*)d_out);
}